// Round 12
// baseline (196.803 us; speedup 1.0000x reference)
//
#include <hip/hip_runtime.h>
#include <hip/hip_bf16.h>

#define BS   2
#define PP   512
#define NN   2048
#define DD   768
#define HH   12
#define HD   64
#define RTOT 2560   // P + N rows per batch
#define QKVC 2304   // 3*D
#define MTOT (BS * RTOT)       // 5120
#define CROWS (BS * HH * NN)   // 49152 cross q-rows
#define SROWS (BS * HH * PP)   // 12288 self q-rows
#define TROWS (CROWS + SROWS)  // 61440

typedef __attribute__((ext_vector_type(8))) short  short8;
typedef __attribute__((ext_vector_type(4))) float  floatx4;

#define MFMA16(a, b, c) __builtin_amdgcn_mfma_f32_16x16x32_bf16(a, b, c, 0, 0, 0)
#define LOG2E 1.4426950408889634f
#define SCL2  0.18033688011112042f   // 0.125 * log2(e)

__device__ __forceinline__ float bf2f(unsigned short x) {
    union { unsigned u; float f; } c; c.u = ((unsigned)x) << 16; return c.f;
}
__device__ __forceinline__ unsigned short f2bf(float x) {
    union { float f; unsigned u; } c; c.f = x;
    unsigned r = c.u + 0x7fff + ((c.u >> 16) & 1);   // RNE
    return (unsigned short)(r >> 16);
}

__device__ __forceinline__ float4 load4(const void* p, size_t i, bool f32) {
    if (f32) return *(const float4*)((const float*)p + i);
    ushort4 u = *(const ushort4*)((const unsigned short*)p + i);
    return make_float4(bf2f(u.x), bf2f(u.y), bf2f(u.z), bf2f(u.w));
}
__device__ __forceinline__ float load1(const void* p, size_t i, bool f32) {
    return f32 ? ((const float*)p)[i] : bf2f(((const unsigned short*)p)[i]);
}
__device__ __forceinline__ bool mask_at(const void* m, int idx, int mtype) {
    if (mtype == 2) return ((const float*)m)[idx] != 0.0f;
    if (mtype == 1) return ((const unsigned char*)m)[idx] != 0;
    return ((const int*)m)[idx] != 0;
}
__device__ __forceinline__ void store_out(float* p, size_t i, float v) { p[i] = v; }
__device__ __forceinline__ void store_out(__hip_bfloat16* p, size_t i, float v) {
    p[i] = __float2bfloat16(v);
}

// async global->LDS, 16B per lane; LDS dest = wave-uniform base + lane*16
__device__ __forceinline__ void gload_lds16(const unsigned short* g, unsigned short* l) {
    __builtin_amdgcn_global_load_lds(
        (const __attribute__((address_space(1))) void*)g,
        (__attribute__((address_space(3))) void*)l,
        16, 0, 0);
}

// XCD-aware block swizzle (T1): dispatch round-robins blocks across the 8
// XCD L2s; remap so each XCD gets a CONTIGUOUS run of logical blocks ->
// panel-sharing neighbors co-reside in one L2. Requires nwg % 8 == 0
// (all our grids: 1920/960/720/480). Bijective.
__device__ __forceinline__ int xcd_swz(int bid, int nwg) {
    return (bid & 7) * (nwg >> 3) + (bid >> 3);
}

// key-position permutation sigma: key bits [n1,n0,g1,g0,r1,r0] stored at
// position [n1,g1,g0,n0,r1,r0]. sigma_pos(k): where key k is stored.
// sigma_inv(p): which key lives at position p.
__device__ __forceinline__ int sigma_pos(int k) {
    return (k & 0x23) | ((k & 0x0C) << 1) | ((k & 0x10) >> 2);
}
__device__ __forceinline__ int sigma_inv(int p) {
    return (p & 0x23) | ((p & 0x18) >> 1) | ((p & 0x04) << 2);
}
// column/dv permutation tau within 64-groups: fragment position p = j*16+li
// holds true column tau(p) = li*4 + j  -> lane's 4 outputs are contiguous.
__device__ __forceinline__ int tau_pos(int p) {           // which col at pos p
    return ((p & 15) << 2) | ((p >> 4) & 3);
}
__device__ __forceinline__ int tau_inv(int c) {           // where col c lives
    return ((c & 3) << 4) | ((c >> 2) & 15);
}

// ---------------------------------------------------------------------------
// Runtime dtype detection + mask->log2-bias table (fused; 1 block).
// ---------------------------------------------------------------------------
__global__ void detect_kernel(const void* __restrict__ w,
                              const void* __restrict__ mask,
                              int* __restrict__ flags,
                              float* __restrict__ mb, int do_mb) {
    __shared__ int s_f32, s_fmask, s_bmask;
    if (threadIdx.x == 0) { s_f32 = 0; s_fmask = 0; s_bmask = 0; }
    __syncthreads();
    const uint4* u4 = (const uint4*)w;
    unsigned acc = 0;
    #pragma unroll
    for (int k = 0; k < 4; k++) {
        uint4 x = u4[k * 256 + threadIdx.x];
        unsigned t0 = x.x & 0x7fff7fffu, t1 = x.y & 0x7fff7fffu;
        unsigned t2 = x.z & 0x7fff7fffu, t3 = x.w & 0x7fff7fffu;
        acc |= (t0 + 0x3fff3fffu) & 0x80008000u;
        acc |= (t1 + 0x3fff3fffu) & 0x80008000u;
        acc |= (t2 + 0x3fff3fffu) & 0x80008000u;
        acc |= (t3 + 0x3fff3fffu) & 0x80008000u;
    }
    if (acc) atomicOr(&s_f32, 1);
    const unsigned* mw = (const unsigned*)mask;
    int fm = 0, bm = 0;
    {
        unsigned v = mw[threadIdx.x];
        if (v == 0x3F800000u) fm = 1;
        else if ((v & 0xFFFFFF00u) != 0u) bm = 1;
    }
    if (fm) atomicOr(&s_fmask, 1);
    if (bm) atomicOr(&s_bmask, 1);
    __syncthreads();
    if (threadIdx.x == 0) {
        flags[0] = s_f32;
        flags[1] = s_fmask ? 2 : (s_bmask ? 1 : 0);
    }
    if (do_mb) {
        const int mtype = s_fmask ? 2 : (s_bmask ? 1 : 0);
        for (int i = threadIdx.x; i < BS * RTOT; i += 256) {
            int b = i / RTOT, m = i % RTOT;
            float v = -15.0f * LOG2E;
            if (m < PP && mask_at(mask, b * PP + m, mtype)) v = -1e30f;
            mb[i] = v;
        }
    }
}

// ---------------------------------------------------------------------------
// Fused prep: blocks [0,MTOT) concat+convert; then Wqkv transpose tiles;
// then Wproj transpose tiles.
// ---------------------------------------------------------------------------
#define TQKV ((QKVC / 64) * (DD / 64))   // 432
#define TPRJ ((DD / 64) * (DD / 64))     // 144
__global__ __launch_bounds__(256) void prep_kernel(
    const void* __restrict__ xq, const void* __restrict__ xs,
    const void* __restrict__ qkv_w, const void* __restrict__ proj_w,
    const int* __restrict__ flags,
    unsigned short* __restrict__ Abf,
    unsigned short* __restrict__ WqkvT,
    unsigned short* __restrict__ WprojT)
{
    const bool f32 = flags[0] != 0;
    __shared__ unsigned short T[64][65];
    int blk = blockIdx.x;
    if (blk < MTOT) {
        if (threadIdx.x < 192) {
            const int r = blk;
            const int b = r / RTOT, rr = r % RTOT;
            const void* src;
            size_t off;
            if (rr < NN) { src = xq; off = (size_t)(b * NN + rr) * DD; }
            else         { src = xs; off = (size_t)(b * PP + (rr - NN)) * DD; }
            const int t = threadIdx.x;
            float4 v = load4(src, off + t * 4, f32);
            ushort4 o;
            o.x = f2bf(v.x); o.y = f2bf(v.y); o.z = f2bf(v.z); o.w = f2bf(v.w);
            *(ushort4*)&Abf[(size_t)r * DD + t * 4] = o;
        }
        return;
    }
    blk -= MTOT;
    const void* in; int R, C; unsigned short* out; int bx;
    if (blk < TQKV) {
        in = qkv_w; R = DD; C = QKVC; out = WqkvT;
        bx = blk % (QKVC / 64);
    } else {
        blk -= TQKV;
        in = proj_w; R = DD; C = DD; out = WprojT;
        bx = blk % (DD / 64);
    }
    const int by = (in == qkv_w) ? (blk / (QKVC / 64)) : (blk / (DD / 64));
    const int c0 = bx * 64, r0 = by * 64;
    const int col = threadIdx.x & 63;
    const int r4  = threadIdx.x >> 6;
    #pragma unroll
    for (int p = 0; p < 16; p++) {
        int row = p * 4 + r4;
        T[row][col] = f2bf(load1(in, (size_t)(r0 + row) * C + c0 + col, f32));
    }
    __syncthreads();
    #pragma unroll
    for (int p = 0; p < 16; p++) {
        int crow = p * 4 + r4;
        out[(size_t)(c0 + crow) * R + r0 + col] = T[col][crow];
    }
}

// ---------------------------------------------------------------------------
// Prep: VtG[(b*HH+h)][rho][m] bf16 = V^T per head, keys sigma-permuted per
// 64-tile, and dv-rows tau-permuted: VtG row rho holds dv = tau_pos(rho), so
// fattn3's O fragment lane li, slot n2 is true dv = li*4+n2 (contiguous).
// ---------------------------------------------------------------------------
__global__ __launch_bounds__(256) void vtprep_kernel(
    const unsigned short* __restrict__ qkv, unsigned short* __restrict__ VtG)
{
    alignas(16) __shared__ unsigned short T[64][72];
    const int mt = blockIdx.x * 64;
    const int bh = blockIdx.y;
    const int b = bh / HH, h = bh % HH;
    const int lr  = threadIdx.x >> 2;
    const int ld0 = (threadIdx.x & 3) << 4;
    const unsigned short* vp = qkv +
        (size_t)(b * RTOT + mt + lr) * QKVC + 2 * DD + h * HD + ld0;
    *(uint4*)&T[lr][ld0]     = ((const uint4*)vp)[0];
    *(uint4*)&T[lr][ld0 + 8] = ((const uint4*)vp)[1];
    __syncthreads();
    const int tdv = tau_pos(lr);               // dv held by this VtG row
    unsigned short tmp[16];
    #pragma unroll
    for (int j = 0; j < 16; j++) {
        const int c = ld0 + j;                 // key storage position
        tmp[j] = T[sigma_inv(c)][tdv];         // V[key sigma_inv(c)][dv tau(lr)]
    }
    unsigned short* dst = VtG + ((size_t)bh * HD + lr) * RTOT + mt + ld0;
    *(uint4*)dst       = *(uint4*)&tmp[0];
    *(uint4*)(dst + 8) = *(uint4*)&tmp[8];
}

// ---------------------------------------------------------------------------
// MFMA GEMM: C[M=128][TN] per block = A @ BT^T + bias.
// global_load_lds staging, linear LDS, XOR chunk swizzle (both-sides).
// B N-columns tau-permuted per 64-group; XCD-swizzled block mapping so
// blocks sharing an A row-panel co-reside on one XCD L2.
// ---------------------------------------------------------------------------
template<int MODE, int NCOL, int TN>
__global__ __launch_bounds__(256) void mgemm_kernel(
    const unsigned short* __restrict__ A,
    const unsigned short* __restrict__ BT,
    const void* __restrict__ bias,
    const int* __restrict__ flags,
    void* __restrict__ outp)
{
    constexpr int MI = (TN == 128) ? 4 : 2;   // 16-row m-frags per wave
    alignas(16) __shared__ unsigned short Ash[128 * 64];
    alignas(16) __shared__ unsigned short Bsh[TN * 64];

    const int tid  = threadIdx.x;
    const int w    = tid >> 6;
    const int lane = tid & 63;
    const int grp  = lane >> 4;
    const int li   = lane & 15;
    const int nbx  = gridDim.x;
    int flat = xcd_swz(blockIdx.y * nbx + blockIdx.x, nbx * gridDim.y);
    const int row0 = (flat / nbx) * 128;
    const int col0 = (flat % nbx) * TN;
    const int moff = (TN == 128) ? (w >> 1) * 64 : w * 32;
    const int noff = (TN == 128) ? (w & 1) * 64 : 0;
    const int srow = lane >> 3;                          // 0..7 within 8-row slab
    const int scol = (((lane & 7) ^ srow) << 3);         // inverse-swizzled src col
    const int lx7  = li & 7;                             // read-side row&7

    floatx4 o[MI][4];
    #pragma unroll
    for (int i = 0; i < MI; i++)
        #pragma unroll
        for (int j = 0; j < 4; j++)
            o[i][j] = (floatx4){0.f, 0.f, 0.f, 0.f};

    for (int k0 = 0; k0 < DD; k0 += 64) {
        __syncthreads();
        #pragma unroll
        for (int i = 0; i < 4; i++) {
            const int rr = w * 32 + i * 8;
            gload_lds16(A + (size_t)(row0 + rr + srow) * DD + k0 + scol,
                        &Ash[rr * 64]);
            if (TN == 128 || w < 2) {
                const int q  = rr + srow;                // B LDS row
                const int bq = (q & ~63) | tau_pos(q & 63);  // tau src row
                gload_lds16(BT + (size_t)(col0 + bq) * DD + k0 + scol,
                            &Bsh[rr * 64]);
            }
        }
        __syncthreads();
        #pragma unroll
        for (int ks = 0; ks < 2; ks++) {
            short8 af[MI], bf[4];
            const int ch = ((ks << 2) + grp) ^ lx7;
            #pragma unroll
            for (int i = 0; i < MI; i++)
                af[i] = *(const short8*)&Ash[(moff + i * 16 + li) * 64 + ch * 8];
            #pragma unroll
            for (int j = 0; j < 4; j++)
                bf[j] = *(const short8*)&Bsh[(noff + j * 16 + li) * 64 + ch * 8];
            #pragma unroll
            for (int i = 0; i < MI; i++)
                #pragma unroll
                for (int j = 0; j < 4; j++)
                    o[i][j] = MFMA16(af[i], bf[j], o[i][j]);
        }
    }

    const bool f32 = flags[0] != 0;
    const int cbase = col0 + noff + li * 4;              // 4 consecutive cols
    float4 b4 = load4(bias, cbase, f32);
    float bv[4] = {b4.x, b4.y, b4.z, b4.w};

    #pragma unroll
    for (int i = 0; i < MI; i++) {
        #pragma unroll
        for (int r = 0; r < 4; r++) {
            int grow = row0 + moff + i * 16 + grp * 4 + r;
            float v0 = o[i][0][r] + bv[0];
            float v1 = o[i][1][r] + bv[1];
            float v2 = o[i][2][r] + bv[2];
            float v3 = o[i][3][r] + bv[3];
            if (MODE == 0) {
                uint2 pk;
                pk.x = (unsigned)f2bf(v0) | ((unsigned)f2bf(v1) << 16);
                pk.y = (unsigned)f2bf(v2) | ((unsigned)f2bf(v3) << 16);
                *(uint2*)&((unsigned short*)outp)[(size_t)grow * NCOL + cbase] = pk;
            } else {
                int b = grow / RTOT, rr2 = grow % RTOT;
                size_t dst = (rr2 < PP)
                    ? ((size_t)(b * PP + rr2) * DD + cbase)
                    : ((size_t)BS * PP * DD + (size_t)(b * NN + (rr2 - PP)) * DD + cbase);
                *(float4*)&((float*)outp)[dst] = make_float4(v0, v1, v2, v3);
            }
        }
    }
}

// ---------------------------------------------------------------------------
// fattn3 (round-8 optimum): 32 queries/wave, swapped QK^T, in-register P,
// V in LDS from sigma+tau-permuted VtG, VALU-accumulated l. XCD-swizzled
// block mapping: the 16 q-blocks sharing one (b,h,chunk) K/V panel become
// contiguous on one XCD L2 (FETCH was 2.4x unique data).
// O fragment slot (li, n2) is true dv = li*4+n2 -> packed uint2 stores.
// ---------------------------------------------------------------------------
template<bool PACKED, int SPL>
__global__ __launch_bounds__(256, 4) void fattn3_kernel(
    const unsigned short* __restrict__ qkv,
    const unsigned short* __restrict__ VtG,      // used if PACKED
    const float* __restrict__ mb,                // log2-domain bias [BS*RTOT]
    unsigned short* __restrict__ attn_out,       // used if SPL==1
    unsigned short* __restrict__ part_o,         // used if SPL>1
    float* __restrict__ part_l)                  // used if SPL>1
{
    const int CB = BS * HH * (NN / 128);   // 384
    const int SB = BS * HH * (PP / 128);   // 96

    int bid = xcd_swz((int)blockIdx.x, (int)gridDim.x);
    bool cross; int chunk, v;
    if (bid < CB * SPL) { cross = true;  chunk = bid / CB; v = bid % CB; }
    else { int s = bid - CB * SPL; cross = false; chunk = s / SB; v = s % SB; }
    const int nqb  = cross ? (NN / 128) : (PP / 128);
    const int q0   = (v % nqb) * 128;
    const int h    = (v / nqb) % HH;
    const int b    = v / (nqb * HH);
    const int QOFF = cross ? PP : 0;
    const int NT   = cross ? (RTOT / 64) : (PP / 64);
    const int tpc  = NT / SPL;
    const int t_beg = chunk * tpc, t_end = chunk * tpc + tpc;
    const int rowbase = cross ? ((b * HH + h) * NN + q0)
                              : (CROWS + (b * HH + h) * PP + q0);

    alignas(16) __shared__ unsigned short Ks[64][72];
    alignas(16) __shared__ unsigned short Vt[64][72];

    const int tid  = threadIdx.x;
    const int w    = tid >> 6;
    const int lane = tid & 63;
    const int grp  = lane >> 4;
    const int li   = lane & 15;
    const int lr   = tid >> 2;
    const int ld0  = (tid & 3) << 4;

    // Q B-frags: 2 q-tiles of 16 per wave (queries q0 + w*32 + qi*16 + li)
    short8 qf[2][2];
    #pragma unroll
    for (int qi = 0; qi < 2; qi++) {
        const unsigned short* qp = qkv +
            (size_t)(b * RTOT + QOFF + q0 + w * 32 + qi * 16 + li) * QKVC
            + h * HD + grp * 8;
        qf[qi][0] = *(const short8*)(qp);
        qf[qi][1] = *(const short8*)(qp + 32);
    }

    floatx4 o[2][4];
    #pragma unroll
    for (int qi = 0; qi < 2; qi++)
        #pragma unroll
        for (int n = 0; n < 4; n++)
            o[qi][n] = (floatx4){0.f, 0.f, 0.f, 0.f};
    float lp[2] = {0.f, 0.f};   // per-lane l partial for query (lane&15)

    // ---- incremental K/V source pointers + first-tile register prefetch ----
    const unsigned short* kptr = qkv +
        (size_t)(b * RTOT + t_beg * 64 + lr) * QKVC + DD + h * HD + ld0;
    const unsigned short* vptr = PACKED
        ? VtG + ((size_t)(b * HH + h) * HD + lr) * RTOT + t_beg * 64 + ld0
        : kptr + DD;
    const float* mbp = mb + b * RTOT + t_beg * 64 + grp * 4;

    uint4 kr0, kr1, vr0, vr1;
    kr0 = ((const uint4*)kptr)[0];
    kr1 = ((const uint4*)kptr)[1];
    vr0 = ((const uint4*)vptr)[0];
    vr1 = ((const uint4*)vptr)[1];
    kptr += (size_t)64 * QKVC;
    vptr += PACKED ? 64 : (size_t)64 * QKVC;

    for (int t = t_beg; t < t_end; t++) {
        __syncthreads();   // all waves done reading Ks/Vt of previous tile
        // ---- stage from registers ----
        *(uint4*)&Ks[lr][ld0]     = kr0;
        *(uint4*)&Ks[lr][ld0 + 8] = kr1;
        if (PACKED) {
            *(uint4*)&Vt[lr][ld0]     = vr0;   // VtG already sigma+tau-permuted
            *(uint4*)&Vt[lr][ld0 + 8] = vr1;
        } else {
            unsigned short tmp[16];
            *(uint4*)&tmp[0] = vr0;
            *(uint4*)&tmp[8] = vr1;
            const int slr = sigma_pos(lr);     // key lr stored at column slr
            #pragma unroll
            for (int j = 0; j < 16; j++)
                Vt[tau_inv(ld0 + j)][slr] = tmp[j];   // dv d at row tau_inv(d)
        }
        __syncthreads();

        // ---- prefetch next tile (overlaps compute) ----
        if (t + 1 < t_end) {
            kr0 = ((const uint4*)kptr)[0];
            kr1 = ((const uint4*)kptr)[1];
            vr0 = ((const uint4*)vptr)[0];
            vr1 = ((const uint4*)vptr)[1];
            kptr += (size_t)64 * QKVC;
            vptr += PACKED ? 64 : (size_t)64 * QKVC;
        }

        // ---- S^T = K Q^T: lane holds P-row of query li, keys n*16+grp*4+r --
        floatx4 sfT[2][4];
        __builtin_amdgcn_s_setprio(1);
        #pragma unroll
        for (int n = 0; n < 4; n++) {
            short8 kb0 = *(const short8*)&Ks[n * 16 + li][grp * 8];
            short8 kb1 = *(const short8*)&Ks[n * 16 + li][32 + grp * 8];
            #pragma unroll
            for (int qi = 0; qi < 2; qi++) {
                floatx4 acc = {0.f, 0.f, 0.f, 0.f};
                acc = MFMA16(kb0, qf[qi][0], acc);
                acc = MFMA16(kb1, qf[qi][1], acc);
                sfT[qi][n] = acc;
            }
        }
        __builtin_amdgcn_s_setprio(0);

        floatx4 mbv[4];
        #pragma unroll
        for (int n = 0; n < 4; n++)
            mbv[n] = *(const floatx4*)(mbp + n * 16);
        mbp += 64;

        // ---- softmax in log2 domain; trunc-bf16 P packed in-register into
        //      the PV A-fragment (sigma key order) ----
        short8 pa[2][2];
        #pragma unroll
        for (int qi = 0; qi < 2; qi++) {
            unsigned u[4][4];
            #pragma unroll
            for (int n = 0; n < 4; n++) {
                #pragma unroll
                for (int r = 0; r < 4; r++) {
                    float e = __builtin_amdgcn_exp2f(
                        fmaf(sfT[qi][n][r], SCL2, mbv[n][r]));
                    u[n][r] = __float_as_uint(e);
                    lp[qi] += __uint_as_float(u[n][r] & 0xffff0000u);
                }
            }
            #pragma unroll
            for (int s2 = 0; s2 < 2; s2++) {
                uint4 pk;
                pk.x = __builtin_amdgcn_perm(u[2*s2][1],   u[2*s2][0],   0x07060302u);
                pk.y = __builtin_amdgcn_perm(u[2*s2][3],   u[2*s2][2],   0x07060302u);
                pk.z = __builtin_amdgcn_perm(u[2*s2+1][1], u[2*s2+1][0], 0x07060302u);
                pk.w = __builtin_amdgcn_perm(u[2*s2+1][3], u[2*s2+1][2], 0x07060302u);
                pa[qi][s2] = __builtin_bit_cast(short8, pk);
            }
        }

        // ---- O += P V (P in registers; O slot n2 = true dv li*4+n2) ----
        __builtin_amdgcn_s_setprio(1);
        #pragma unroll
        for (int s2 = 0; s2 < 2; s2++) {
            #pragma unroll
            for (int n2 = 0; n2 < 4; n2++) {
                short8 vf = *(const short8*)&Vt[n2 * 16 + li][s2 * 32 + grp * 8];
                o[0][n2] = MFMA16(pa[0][s2], vf, o[0][n2]);
                o[1][n2] = MFMA16(pa[1][s2], vf, o[1][n2]);
            }
        }
        __builtin_amdgcn_s_setprio(0);
    }

    // ---- l reduction: sum the 4 grp-partials for each query ----
    float lfull[2];
    #pragma unroll
    for (int qi = 0; qi < 2; qi++) {
        float l = lp[qi];
        l += __shfl_xor(l, 16);
        l += __shfl_xor(l, 32);
        lfull[qi] = l;    // value for query (lane&15), replicated across grps
    }

    // ---- epilogue: dv of o[qi][n2][r] is li*4+n2 -> packed uint2 stores ----
    if (SPL > 1) {
        #pragma unroll
        for (int qi = 0; qi < 2; qi++)
            #pragma unroll
            for (int r = 0; r < 4; r++) {
                float lv = __shfl(lfull[qi], grp * 4 + r);
                size_t row = (size_t)chunk * TROWS + rowbase
                           + w * 32 + qi * 16 + grp * 4 + r;
                uint2 pk;
                pk.x = (unsigned)f2bf(o[qi][0][r]) | ((unsigned)f2bf(o[qi][1][r]) << 16);
                pk.y = (unsigned)f2bf(o[qi][2][r]) | ((unsigned)f2bf(o[qi][3][r]) << 16);
                *(uint2*)&part_o[row * 64 + li * 4] = pk;
                if (li == 0) part_l[row] = lv;
            }
    } else {
        #pragma unroll
        for (int qi = 0; qi < 2; qi++)
            #pragma unroll
            for (int r = 0; r < 4; r++) {
                float inv = 1.0f / __shfl(lfull[qi], grp * 4 + r);
                int qloc = q0 + w * 32 + qi * 16 + grp * 4 + r;
                if (cross) {
                    size_t row = (size_t)(b * RTOT + PP + qloc);
                    uint2 pk;
                    pk.x = (unsigned)f2bf(o[qi][0][r] * inv)
                         | ((unsigned)f2bf(o[qi][1][r] * inv) << 16);
                    pk.y = (unsigned)f2bf(o[qi][2][r] * inv)
                         | ((unsigned)f2bf(o[qi][3][r] * inv) << 16);
                    *(uint2*)&attn_out[row * DD + h * HD + li * 4] = pk;
                } else {
                    #pragma unroll
                    for (int n2 = 0; n2 < 4; n2++) {
                        int dc = li * 4 + n2;
                        int f = h * (HD * PP) + dc * PP + qloc;
                        attn_out[(size_t)(b * RTOT + f / DD) * DD + (f % DD)]
                            = f2bf(o[qi][n2][r] * inv);
                    }
                }
            }
    }
}

// ---------------------------------------------------------------------------
// Split-K combine. Cross rows: contiguous writes. Self rows: 64-row LDS
// transpose -> contiguous 32B writes.
// ---------------------------------------------------------------------------
template<int SPL>
__global__ __launch_bounds__(256) void combine_kernel(
    const unsigned short* __restrict__ part_o,
    const float* __restrict__ part_l,
    unsigned short* __restrict__ attn_out)
{
    const int CBLK = CROWS / 4;            // 12288
    if (blockIdx.x < CBLK) {
        const int row = blockIdx.x * 4 + (threadIdx.x >> 6);
        const int dv  = threadIdx.x & 63;
        float l = 0.f, ov = 0.f;
        #pragma unroll
        for (int c = 0; c < SPL; c++) {
            l  += part_l[(size_t)c * TROWS + row];
            ov += bf2f(part_o[((size_t)c * TROWS + row) * 64 + dv]);
        }
        float res = ov / l;
        int b = row / (HH * NN), rem = row % (HH * NN);
        int h = rem / NN, n = rem % NN;
        attn_out[(size_t)(b * RTOT + PP + n) * DD + h * HD + dv] = f2bf(res);
        return;
    }
    // ---- self rows: 64 rows/block, transpose in LDS ----
    __shared__ unsigned short T[64][72];
    const int blk = blockIdx.x - CBLK;     // 0..SROWS/64-1
    const int r0b = blk * 64;              // offset into self region
    {
        const int rp  = threadIdx.x >> 2;          // row in group
        const int d0  = (threadIdx.x & 3) * 16;
        const int row = CROWS + r0b + rp;
        float l = 0.f;
        float ov[16] = {};
        #pragma unroll
        for (int c = 0; c < SPL; c++) {
            l += part_l[(size_t)c * TROWS + row];
            const uint4* po = (const uint4*)&part_o[((size_t)c * TROWS + row) * 64 + d0];
            uint4 x0 = po[0], x1 = po[1];
            const unsigned short* u0 = (const unsigned short*)&x0;
            const unsigned short* u1 = (const unsigned short*)&x1;
            #pragma unroll
            for (int k = 0; k < 8; k++) { ov[k] += bf2f(u0[k]); ov[8 + k] += bf2f(u1[k]); }
        }
        float inv = 1.0f / l;
        #pragma unroll
        for (int k = 0; k < 16; k++) T[rp][d0 + k] = f2bf(ov[k] * inv);
    }
    __syncthreads();
    {
        const int dv = threadIdx.x >> 2;
        const int pc = (threadIdx.x & 3) * 16;
        const int bh = r0b / PP;           // b*HH + h
        const int p0 = r0b % PP;
        const int b = bh / HH, h = bh % HH;
        unsigned short tmp[16];
        #pragma unroll
        for (int k = 0; k < 16; k++) tmp[k] = T[pc + k][dv];
        size_t base = (size_t)b * RTOT * DD + (size_t)h * (HD * PP)
                    + (size_t)dv * PP + p0 + pc;
        *(uint4*)&attn_out[base]     = *(uint4*)&tmp[0];
        *(uint4*)&attn_out[base + 8] = *(uint4*)&tmp[8];
    }
}

// ---------------------------------------------------------------------------
// Round-9 fattn (fallback tier, online softmax, reads mask directly).
// ---------------------------------------------------------------------------
template<int MODE>
__global__ __launch_bounds__(256) void fattn_kernel(
    const __hip_bfloat16* __restrict__ qkv,
    const void* __restrict__ mask,
    const int* __restrict__ flags,
    __hip_bfloat16* __restrict__ attn_out)
{
    constexpr int NQ    = (MODE == 0) ? NN : PP;
    constexpr int NK    = (MODE == 0) ? RTOT : PP;
    constexpr int QOFF  = (MODE == 0) ? PP : 0;
    constexpr int NTILE = NK / 64;

    alignas(16) __shared__ unsigned short Ks[64][72];
    alignas(16) __shared__ unsigned short Vt[64][72];
    alignas(16) __shared__ unsigned short Psm[4][16][72];

    const int tid   = threadIdx.x;
    const int w     = tid >> 6;
    const int lane  = tid & 63;
    const int grp   = lane >> 4;
    const int li    = lane & 15;
    const int nqb   = NQ / 64;
    const int q0    = (blockIdx.x % nqb) * 64;
    const int h     = (blockIdx.x / nqb) % HH;
    const int b     = blockIdx.x / (nqb * HH);
    const int mtype = flags[1];

    const unsigned short* qkv_u = (const unsigned short*)qkv;
    const int lr  = tid >> 2;
    const int ld0 = (tid & 3) << 4;

    short8 qf[2];
    {
        const unsigned short* qp = qkv_u +
            (size_t)(b * RTOT + QOFF + q0 + w * 16 + li) * QKVC + h * HD + grp * 8;
        qf[0] = *(const short8*)(qp);
        qf[1] = *(const short8*)(qp + 32);
    }

    floatx4 o[4] = {{0.f,0.f,0.f,0.f},{0.f,0.f,0.f,0.f},
                    {0.f,0.f,0.f,0.f},{0.f,0.f,0.f,0.f}};
    float mrun[4] = {-3e38f, -3e38f, -3e38f, -3e38f};
    float lrun[4] = {0.f, 0.f, 0.f, 0.f};

    for (int t = 0; t < NTILE; t++) {
        const int m0 = t * 64;
        __syncthreads();
        {
            const unsigned short* kp = qkv_u +
                (size_t)(b * RTOT + m0 + lr) * QKVC + DD + h * HD + ld0;
            *(uint4*)&Ks[lr][ld0]     = ((const uint4*)kp)[0];
            *(uint4*)&Ks[lr][ld0 + 8] = ((const uint4*)kp)[1];
            const unsigned short* vp = kp + DD;
            unsigned short tmp[16];
            *(uint4*)&tmp[0] = ((const uint4*)vp)[0];
            *(uint4*)&tmp[8] = ((const uint4*)vp)[1];
            #pragma unroll
            for (int j = 0; j < 16; j++) Vt[ld0 + j][lr] = tmp[j];
        }
        __syncthreads();

        floatx4 sf[4];
        #pragma unroll
        for (int n = 0; n < 4; n++) {
            floatx4 acc = {0.f, 0.f, 0.f, 0.f};
            short8 kb0 = *(const short8*)&Ks[n * 16 + li][grp * 8];
            short8 kb1 = *(const short8*)&Ks[n * 16 + li][32 + grp * 8];
            acc = MFMA16(qf[0], kb0, acc);
            acc = MFMA16(qf[1], kb1, acc);
            sf[n] = acc;
        }

        bool mk[4];
        #pragma unroll
        for (int n = 0; n < 4; n++) {
            int m = m0 + n * 16 + li;
            mk[n] = (m < PP) && mask_at(mask, b * PP + m, mtype);
        }

        #pragma unroll
        for (int r = 0; r < 4; r++) {
            float sv[4];
            #pragma unroll
            for (int n = 0; n < 4; n++)
                sv[n] = mk[n] ? -1e30f : sf[n][r] * 0.125f;
            float tm = fmaxf(fmaxf(sv[0], sv[1]), fmaxf(sv[2], sv[3]));
            #pragma unroll
            for (int off = 1; off < 16; off <<= 1)
                tm = fmaxf(tm, __shfl_xor(tm, off));
            float mnew = fmaxf(mrun[r], tm);
            float al = __expf(mrun[r] - mnew);
            float p[4], ts = 0.f;
            #pragma unroll
            for (int n = 0; n < 4; n++) {
                p[n] = (sv[n] < -1e29f) ? 0.f : __expf(sv[n] - mnew);
                ts += p[n];
            }
            #pragma unroll
            for (int off = 1; off < 16; off <<= 1)
                ts += __shfl_xor(ts, off);
            mrun[r] = mnew;
            lrun[r] = lrun[r] * al + ts;
            #pragma unroll
            for (int n = 0; n < 4; n++) {
                o[n][r] *= al;
                Psm[w][grp * 4 + r][n * 16 + li] = f2bf(p[n]);
            }
        }
        __syncthreads();

        #pragma unroll
        for (int s2 = 0; s2 < 2; s2++) {
            short8 pa = *(const short8*)&Psm[w][li][s2 * 32 + grp * 8];
            #pragma unroll
            for (int n2 = 0; n2 < 4; n2++) {
                short8 vf = *(const short8*)&Vt[n2 * 16 + li][s2 * 32 + grp * 8];
                o[n2] = MFMA16(pa, vf, o[n2]);
            }
        }
    }

    unsigned short* ao = (unsigned short*)attn_out;
    #pragma unroll
    for (int r = 0; r < 4; r++) {
        float inv = 1.0f / lrun[r];
        int qloc = q0 + w * 16 + grp * 4 + r;
        if (MODE == 0) {
            size_t row = (size_t)(b * RTOT + PP + qloc);
            #pragma unroll
            for (int n2 = 0; n2 < 4; n2++)
                ao[row * DD + h * HD + n2 * 16 + li] = f2bf(o[n2][r] * inv);
        } else {
            #pragma unroll
            for (int n2 = 0; n2 < 4; n2++) {
                int dc = n2 * 16 + li;
                int f = h * (HD * PP) + dc * PP + qloc;
                ao[(size_t)(b * RTOT + f / DD) * DD + (f % DD)] = f2bf(o[n2][r] * inv);
            }
        }
    }
}

// ---------------------------------------------------------------------------
// Vector GEMM fallback (last-resort tier).
// ---------------------------------------------------------------------------
template<int MODE, int NCOL, typename OutT>
__global__ __launch_bounds__(256) void gemm_kernel(
    const void* __restrict__ A0, const void* __restrict__ A1,
    const void* __restrict__ W, const void* __restrict__ bias,
    const int* __restrict__ flags, OutT* __restrict__ out)
{
    const bool f32 = flags[0] != 0;
    alignas(16) __shared__ float As[16][68];
    alignas(16) __shared__ float Bsh2[16][68];
    const int tid  = threadIdx.x;
    const int row0 = blockIdx.y * 64;
    const int col0 = blockIdx.x * 64;
    const int ty = tid >> 4, tx = tid & 15;
    const int a_row = tid >> 2;
    const int a_k4  = (tid & 3) * 4;
    const int grow  = row0 + a_row;
    const void* abase; size_t aoff; bool af32;
    if (MODE == 0) {
        int b = grow / RTOT, r = grow % RTOT;
        if (r < NN) { abase = A0; aoff = (size_t)(b * NN + r) * DD; }
        else        { abase = A1; aoff = (size_t)(b * PP + (r - NN)) * DD; }
        af32 = f32;
    } else {
        abase = A0; aoff = (size_t)grow * DD; af32 = false;
    }
    const int b_k  = tid >> 4;
    const int b_n4 = (tid & 15) * 4;
    float acc[4][4] = {};
    for (int k0 = 0; k0 < DD; k0 += 16) {
        float4 fa = load4(abase, aoff + k0 + a_k4, af32);
        As[a_k4 + 0][a_row] = fa.x;
        As[a_k4 + 1][a_row] = fa.y;
        As[a_k4 + 2][a_row] = fa.z;
        As[a_k4 + 3][a_row] = fa.w;
        float4 fb = load4(W, (size_t)(k0 + b_k) * NCOL + col0 + b_n4, f32);
        *(float4*)&Bsh2[b_k][b_n4] = fb;
        __syncthreads();
        #pragma unroll
        for (int kk = 0; kk < 16; kk++) {
            float4 av = *(const float4*)&As[kk][ty * 4];
            float4 bvv = *(const float4*)&Bsh2[kk][tx * 4];
            float a_[4] = {av.x, av.y, av.z, av.w};
            float b_[4] = {bvv.x, bvv.y, bvv.z, bvv.w};
            #pragma unroll
            for (int i = 0; i < 4; i++)
                #pragma unroll
                for (int j = 0; j < 4; j++)
                    acc[i][j] += a_[i] * b_[j];
        }
        __syncthreads();
    }
    #pragma unroll
    for (int i = 0; i < 4; i++) {
        int gr = row0 + ty * 4 + i;
        #pragma unroll
        for (int j = 0; j < 4; j++) {
            int gc = col0 + tx * 4 + j;
            float v = acc[i][j] + load1(bias, gc, f32);
            if (MODE == 0) {
                store_out(out, (size_t)gr * NCOL + gc, v);
            } else {
                int b = gr / RTOT, r = gr % RTOT;
                size_t dst = (r < PP)
                    ? ((size_t)(b * PP + r) * DD + gc)
                    : ((size_t)BS * PP * DD + (size_t)(b * NN + (r - PP)) * DD + gc);
                store_out(out, dst, v);
            }
        }
    }
}

// ---------------------------------------------------------------------------
extern "C" void kernel_launch(void* const* d_in, const int* in_sizes, int n_in,
                              void* d_out, int out_size, void* d_ws, size_t ws_size,
                              hipStream_t stream) {
    const void *xs = nullptr, *xq = nullptr, *mask = nullptr,
               *qkv_w = nullptr, *qkv_b = nullptr, *proj_w = nullptr, *proj_b = nullptr;
    for (int i = 0; i < n_in; i++) {
        switch (in_sizes[i]) {
            case BS * PP * DD:   xs     = d_in[i]; break;
            case BS * NN * DD:   xq     = d_in[i]; break;
            case BS * PP:        mask   = d_in[i]; break;
            case DD * QKVC:      qkv_w  = d_in[i]; break;
            case QKVC:           qkv_b  = d_in[i]; break;
            case DD * DD:        proj_w = d_in[i]; break;
            case DD:             proj_b = d_in[i]; break;
        }
    }
    if (!xs || !xq || !mask || !qkv_w || !qkv_b || !proj_w || !proj_b) {
        xs = d_in[0]; xq = d_in[1]; mask = d_in[2];
        qkv_w = d_in[3]; qkv_b = d_in[4]; proj_w = d_in[5]; proj_b = d_in[6];
    }
    float* out = (float*)d_out;

    const size_t off_mb   = 256;
    const size_t off_full = off_mb   + (size_t)BS * RTOT * 4;
    const size_t off_ab   = off_full + (size_t)MTOT * QKVC * 2;
    const size_t off_w    = off_ab   + (size_t)MTOT * DD * 2;
    const size_t off_wp   = off_w    + (size_t)QKVC * DD * 2;
    const size_t off_vt   = off_wp   + (size_t)DD * DD * 2;
    const size_t off_po   = off_vt   + (size_t)BS * HH * HD * RTOT * 2;
    // SPL=4 tier
    const size_t off_ml4  = off_po   + (size_t)4 * TROWS * 64 * 2;
    const size_t need_A4  = off_ml4  + (size_t)4 * TROWS * 4;
    // SPL=2 tier
    const size_t off_ml2  = off_po   + (size_t)2 * TROWS * 64 * 2;
    const size_t need_A2  = off_ml2  + (size_t)2 * TROWS * 4;
    const size_t need_B   = off_po;
    const size_t need_C   = off_vt;

    const size_t r_full = 256;
    const size_t r_ab   = r_full + (size_t)MTOT * QKVC * 2;
    const size_t r_wq   = r_ab   + (size_t)MTOT * DD * 2;
    const size_t r_wp   = r_wq   + (size_t)QKVC * DD * 2;
    const size_t need_R = r_wp   + (size_t)DD * DD * 2;

    int* flags = (int*)d_ws;
    const int NCMB = CROWS / 4 + SROWS / 64;   // combine grid

    if (ws_size >= need_C) {
        float* mb               = (float*)((char*)d_ws + off_mb);
        unsigned short* fullqkv = (unsigned short*)((char*)d_ws + off_full);
        unsigned short* attn    = (unsigned short*)((char*)d_ws + off_ab);
        unsigned short* WqkvT   = (unsigned short*)((char*)d_ws + off_w);
        unsigned short* WprojT  = (unsigned short*)((char*)d_ws + off_wp);
        unsigned short* VtG     = (unsigned short*)((char*)d_ws + off_vt);
        unsigned short* part_o  = (unsigned short*)((char*)d_ws + off_po);

        detect_kernel<<<1, 256, 0, stream>>>(qkv_w, mask, flags, mb, 1);
        prep_kernel<<<MTOT + TQKV + TPRJ, 256, 0, stream>>>(
            xq, xs, qkv_w, proj_w, flags, attn /*as Abf*/, WqkvT, WprojT);

        mgemm_kernel<0, QKVC, 128><<<dim3(QKVC / 128, MTOT / 128), 256, 0, stream>>>(
            attn /*Abf*/, WqkvT, qkv_b, flags, (void*)fullqkv);

        const int CB = BS * HH * (NN / 128), SB = BS * HH * (PP / 128);
        if (ws_size >= need_A4) {
            float* part_l = (float*)((char*)d_ws + off_ml4);
            vtprep_kernel<<<dim3(RTOT / 64, BS * HH), 256, 0, stream>>>(fullqkv, VtG);
            fattn3_kernel<true, 4><<<(CB + SB) * 4, 256, 0, stream>>>(
                fullqkv, VtG, mb, nullptr, part_o, part_l);
            combine_kernel<4><<<NCMB, 256, 0, stream>>>(part_o, part_l, attn);
        } else if (ws_size >= need_A2) {
            float* part_l = (float*)((char*)d_ws + off_ml2);
            vtprep_kernel<<<dim3(RTOT / 64, BS * HH), 256, 0, stream>>>(fullqkv, VtG);
            fattn3_kernel<true, 2><<<(CB + SB) * 2, 256, 0, stream>>>(
                fullqkv, VtG, mb, nullptr, part_o, part_l);
            combine_kernel<2><<<NCMB, 256, 0, stream>>>(part_o, part_l, attn);
        } else if (ws_size >= need_B) {
            vtprep_kernel<<<dim3(RTOT / 64, BS * HH), 256, 0, stream>>>(fullqkv, VtG);
            fattn3_kernel<true, 1><<<CB + SB, 256, 0, stream>>>(
                fullqkv, VtG, mb, attn, nullptr, nullptr);
        } else {
            fattn3_kernel<false, 1><<<CB + SB, 256, 0, stream>>>(
                fullqkv, nullptr, mb, attn, nullptr, nullptr);
        }

        mgemm_kernel<1, DD, 64><<<dim3(DD / 64, MTOT / 128), 256, 0, stream>>>(
            attn, WprojT, proj_b, flags, (void*)out);
    } else if (ws_size >= need_R) {
        unsigned short* fullqkv = (unsigned short*)((char*)d_ws + r_full);
        unsigned short* attn    = (unsigned short*)((char*)d_ws + r_ab);
        unsigned short* WqkvT   = (unsigned short*)((char*)d_ws + r_wq);
        unsigned short* WprojT  = (unsigned short*)((char*)d_ws + r_wp);

        detect_kernel<<<1, 256, 0, stream>>>(qkv_w, mask, flags, nullptr, 0);
        prep_kernel<<<MTOT + TQKV + TPRJ, 256, 0, stream>>>(
            xq, xs, qkv_w, proj_w, flags, attn, WqkvT, WprojT);
        mgemm_kernel<0, QKVC, 128><<<dim3(QKVC / 128, MTOT / 128), 256, 0, stream>>>(
            attn, WqkvT, qkv_b, flags, (void*)fullqkv);
        fattn_kernel<0><<<BS * HH * (NN / 64), 256, 0, stream>>>(
            (const __hip_bfloat16*)fullqkv, mask, flags, (__hip_bfloat16*)attn);
        fattn_kernel<1><<<BS * HH * (PP / 64), 256, 0, stream>>>(
            (const __hip_bfloat16*)fullqkv, mask, flags, (__hip_bfloat16*)attn);
        mgemm_kernel<1, DD, 64><<<dim3(DD / 64, MTOT / 128), 256, 0, stream>>>(
            attn, WprojT, proj_b, flags, (void*)out);
    } else {
        __hip_bfloat16* fullqkv = (__hip_bfloat16*)((char*)d_ws + 256);
        __hip_bfloat16* attn    = fullqkv + (size_t)MTOT * QKVC;
        detect_kernel<<<1, 256, 0, stream>>>(qkv_w, mask, flags, nullptr, 0);
        gemm_kernel<0, QKVC, __hip_bfloat16>
            <<<dim3(QKVC / 64, MTOT / 64), 256, 0, stream>>>(
            xq, xs, qkv_w, qkv_b, flags, fullqkv);
        fattn_kernel<0><<<BS * HH * (NN / 64), 256, 0, stream>>>(fullqkv, mask, flags, attn);
        fattn_kernel<1><<<BS * HH * (PP / 64), 256, 0, stream>>>(fullqkv, mask, flags, attn);
        gemm_kernel<1, DD, float>
            <<<dim3(DD / 64, MTOT / 64), 256, 0, stream>>>(
            attn, nullptr, proj_w, proj_b, flags, out);
    }
}

// Round 13
// 187.203 us; speedup vs baseline: 1.0513x; 1.0513x over previous
//
#include <hip/hip_runtime.h>
#include <hip/hip_bf16.h>

#define BS   2
#define PP   512
#define NN   2048
#define DD   768
#define HH   12
#define HD   64
#define RTOT 2560   // P + N rows per batch
#define QKVC 2304   // 3*D
#define MTOT (BS * RTOT)       // 5120
#define CROWS (BS * HH * NN)   // 49152 cross q-rows
#define SROWS (BS * HH * PP)   // 12288 self q-rows
#define TROWS (CROWS + SROWS)  // 61440

typedef __attribute__((ext_vector_type(8))) short  short8;
typedef __attribute__((ext_vector_type(4))) float  floatx4;

#define MFMA16(a, b, c) __builtin_amdgcn_mfma_f32_16x16x32_bf16(a, b, c, 0, 0, 0)
#define LOG2E 1.4426950408889634f
#define SCL2  0.18033688011112042f   // 0.125 * log2(e)

__device__ __forceinline__ float bf2f(unsigned short x) {
    union { unsigned u; float f; } c; c.u = ((unsigned)x) << 16; return c.f;
}
__device__ __forceinline__ unsigned short f2bf(float x) {
    union { float f; unsigned u; } c; c.f = x;
    unsigned r = c.u + 0x7fff + ((c.u >> 16) & 1);   // RNE
    return (unsigned short)(r >> 16);
}

__device__ __forceinline__ float4 load4(const void* p, size_t i, bool f32) {
    if (f32) return *(const float4*)((const float*)p + i);
    ushort4 u = *(const ushort4*)((const unsigned short*)p + i);
    return make_float4(bf2f(u.x), bf2f(u.y), bf2f(u.z), bf2f(u.w));
}
__device__ __forceinline__ float load1(const void* p, size_t i, bool f32) {
    return f32 ? ((const float*)p)[i] : bf2f(((const unsigned short*)p)[i]);
}
__device__ __forceinline__ bool mask_at(const void* m, int idx, int mtype) {
    if (mtype == 2) return ((const float*)m)[idx] != 0.0f;
    if (mtype == 1) return ((const unsigned char*)m)[idx] != 0;
    return ((const int*)m)[idx] != 0;
}
__device__ __forceinline__ void store_out(float* p, size_t i, float v) { p[i] = v; }
__device__ __forceinline__ void store_out(__hip_bfloat16* p, size_t i, float v) {
    p[i] = __float2bfloat16(v);
}

// async global->LDS, 16B per lane; LDS dest = wave-uniform base + lane*16
__device__ __forceinline__ void gload_lds16(const unsigned short* g, unsigned short* l) {
    __builtin_amdgcn_global_load_lds(
        (const __attribute__((address_space(1))) void*)g,
        (__attribute__((address_space(3))) void*)l,
        16, 0, 0);
}

// XCD-aware block swizzle (T1): dispatch round-robins blocks across the 8
// XCD L2s; remap so each XCD gets a CONTIGUOUS run of logical blocks ->
// panel-sharing neighbors co-reside in one L2. Uniform-cost grids only
// (mgemm); fattn3 uses the region-balanced variant below. nwg % 8 == 0.
__device__ __forceinline__ int xcd_swz(int bid, int nwg) {
    return (bid & 7) * (nwg >> 3) + (bid >> 3);
}

// key-position permutation sigma: key bits [n1,n0,g1,g0,r1,r0] stored at
// position [n1,g1,g0,n0,r1,r0]. sigma_pos(k): where key k is stored.
// sigma_inv(p): which key lives at position p.
__device__ __forceinline__ int sigma_pos(int k) {
    return (k & 0x23) | ((k & 0x0C) << 1) | ((k & 0x10) >> 2);
}
__device__ __forceinline__ int sigma_inv(int p) {
    return (p & 0x23) | ((p & 0x18) >> 1) | ((p & 0x04) << 2);
}
// column/dv permutation tau within 64-groups: fragment position p = j*16+li
// holds true column tau(p) = li*4 + j  -> lane's 4 outputs are contiguous.
__device__ __forceinline__ int tau_pos(int p) {           // which col at pos p
    return ((p & 15) << 2) | ((p >> 4) & 3);
}
__device__ __forceinline__ int tau_inv(int c) {           // where col c lives
    return ((c & 3) << 4) | ((c >> 2) & 15);
}

// ---------------------------------------------------------------------------
// Runtime dtype detection + mask->log2-bias table (fused; 1 block).
// ---------------------------------------------------------------------------
__global__ void detect_kernel(const void* __restrict__ w,
                              const void* __restrict__ mask,
                              int* __restrict__ flags,
                              float* __restrict__ mb, int do_mb) {
    __shared__ int s_f32, s_fmask, s_bmask;
    if (threadIdx.x == 0) { s_f32 = 0; s_fmask = 0; s_bmask = 0; }
    __syncthreads();
    const uint4* u4 = (const uint4*)w;
    unsigned acc = 0;
    #pragma unroll
    for (int k = 0; k < 4; k++) {
        uint4 x = u4[k * 256 + threadIdx.x];
        unsigned t0 = x.x & 0x7fff7fffu, t1 = x.y & 0x7fff7fffu;
        unsigned t2 = x.z & 0x7fff7fffu, t3 = x.w & 0x7fff7fffu;
        acc |= (t0 + 0x3fff3fffu) & 0x80008000u;
        acc |= (t1 + 0x3fff3fffu) & 0x80008000u;
        acc |= (t2 + 0x3fff3fffu) & 0x80008000u;
        acc |= (t3 + 0x3fff3fffu) & 0x80008000u;
    }
    if (acc) atomicOr(&s_f32, 1);
    const unsigned* mw = (const unsigned*)mask;
    int fm = 0, bm = 0;
    {
        unsigned v = mw[threadIdx.x];
        if (v == 0x3F800000u) fm = 1;
        else if ((v & 0xFFFFFF00u) != 0u) bm = 1;
    }
    if (fm) atomicOr(&s_fmask, 1);
    if (bm) atomicOr(&s_bmask, 1);
    __syncthreads();
    if (threadIdx.x == 0) {
        flags[0] = s_f32;
        flags[1] = s_fmask ? 2 : (s_bmask ? 1 : 0);
    }
    if (do_mb) {
        const int mtype = s_fmask ? 2 : (s_bmask ? 1 : 0);
        for (int i = threadIdx.x; i < BS * RTOT; i += 256) {
            int b = i / RTOT, m = i % RTOT;
            float v = -15.0f * LOG2E;
            if (m < PP && mask_at(mask, b * PP + m, mtype)) v = -1e30f;
            mb[i] = v;
        }
    }
}

// ---------------------------------------------------------------------------
// Fused prep: blocks [0,MTOT) concat+convert; then Wqkv transpose tiles;
// then Wproj transpose tiles.
// ---------------------------------------------------------------------------
#define TQKV ((QKVC / 64) * (DD / 64))   // 432
#define TPRJ ((DD / 64) * (DD / 64))     // 144
__global__ __launch_bounds__(256) void prep_kernel(
    const void* __restrict__ xq, const void* __restrict__ xs,
    const void* __restrict__ qkv_w, const void* __restrict__ proj_w,
    const int* __restrict__ flags,
    unsigned short* __restrict__ Abf,
    unsigned short* __restrict__ WqkvT,
    unsigned short* __restrict__ WprojT)
{
    const bool f32 = flags[0] != 0;
    __shared__ unsigned short T[64][65];
    int blk = blockIdx.x;
    if (blk < MTOT) {
        if (threadIdx.x < 192) {
            const int r = blk;
            const int b = r / RTOT, rr = r % RTOT;
            const void* src;
            size_t off;
            if (rr < NN) { src = xq; off = (size_t)(b * NN + rr) * DD; }
            else         { src = xs; off = (size_t)(b * PP + (rr - NN)) * DD; }
            const int t = threadIdx.x;
            float4 v = load4(src, off + t * 4, f32);
            ushort4 o;
            o.x = f2bf(v.x); o.y = f2bf(v.y); o.z = f2bf(v.z); o.w = f2bf(v.w);
            *(ushort4*)&Abf[(size_t)r * DD + t * 4] = o;
        }
        return;
    }
    blk -= MTOT;
    const void* in; int R, C; unsigned short* out; int bx;
    if (blk < TQKV) {
        in = qkv_w; R = DD; C = QKVC; out = WqkvT;
        bx = blk % (QKVC / 64);
    } else {
        blk -= TQKV;
        in = proj_w; R = DD; C = DD; out = WprojT;
        bx = blk % (DD / 64);
    }
    const int by = (in == qkv_w) ? (blk / (QKVC / 64)) : (blk / (DD / 64));
    const int c0 = bx * 64, r0 = by * 64;
    const int col = threadIdx.x & 63;
    const int r4  = threadIdx.x >> 6;
    #pragma unroll
    for (int p = 0; p < 16; p++) {
        int row = p * 4 + r4;
        T[row][col] = f2bf(load1(in, (size_t)(r0 + row) * C + c0 + col, f32));
    }
    __syncthreads();
    #pragma unroll
    for (int p = 0; p < 16; p++) {
        int crow = p * 4 + r4;
        out[(size_t)(c0 + crow) * R + r0 + col] = T[col][crow];
    }
}

// ---------------------------------------------------------------------------
// Prep: VtG[(b*HH+h)][rho][m] bf16 = V^T per head, keys sigma-permuted per
// 64-tile, and dv-rows tau-permuted: VtG row rho holds dv = tau_pos(rho), so
// fattn3's O fragment lane li, slot n2 is true dv = li*4+n2 (contiguous).
// ---------------------------------------------------------------------------
__global__ __launch_bounds__(256) void vtprep_kernel(
    const unsigned short* __restrict__ qkv, unsigned short* __restrict__ VtG)
{
    alignas(16) __shared__ unsigned short T[64][72];
    const int mt = blockIdx.x * 64;
    const int bh = blockIdx.y;
    const int b = bh / HH, h = bh % HH;
    const int lr  = threadIdx.x >> 2;
    const int ld0 = (threadIdx.x & 3) << 4;
    const unsigned short* vp = qkv +
        (size_t)(b * RTOT + mt + lr) * QKVC + 2 * DD + h * HD + ld0;
    *(uint4*)&T[lr][ld0]     = ((const uint4*)vp)[0];
    *(uint4*)&T[lr][ld0 + 8] = ((const uint4*)vp)[1];
    __syncthreads();
    const int tdv = tau_pos(lr);               // dv held by this VtG row
    unsigned short tmp[16];
    #pragma unroll
    for (int j = 0; j < 16; j++) {
        const int c = ld0 + j;                 // key storage position
        tmp[j] = T[sigma_inv(c)][tdv];         // V[key sigma_inv(c)][dv tau(lr)]
    }
    unsigned short* dst = VtG + ((size_t)bh * HD + lr) * RTOT + mt + ld0;
    *(uint4*)dst       = *(uint4*)&tmp[0];
    *(uint4*)(dst + 8) = *(uint4*)&tmp[8];
}

// ---------------------------------------------------------------------------
// MFMA GEMM: C[M=128][TN] per block = A @ BT^T + bias.
// global_load_lds staging, linear LDS, XOR chunk swizzle (both-sides).
// B N-columns tau-permuted per 64-group; XCD-swizzled block mapping (uniform
// cost per block -> no imbalance) so A-panel-sharing blocks share one L2.
// ---------------------------------------------------------------------------
template<int MODE, int NCOL, int TN>
__global__ __launch_bounds__(256) void mgemm_kernel(
    const unsigned short* __restrict__ A,
    const unsigned short* __restrict__ BT,
    const void* __restrict__ bias,
    const int* __restrict__ flags,
    void* __restrict__ outp)
{
    constexpr int MI = (TN == 128) ? 4 : 2;   // 16-row m-frags per wave
    alignas(16) __shared__ unsigned short Ash[128 * 64];
    alignas(16) __shared__ unsigned short Bsh[TN * 64];

    const int tid  = threadIdx.x;
    const int w    = tid >> 6;
    const int lane = tid & 63;
    const int grp  = lane >> 4;
    const int li   = lane & 15;
    const int nbx  = gridDim.x;
    int flat = xcd_swz(blockIdx.y * nbx + blockIdx.x, nbx * gridDim.y);
    const int row0 = (flat / nbx) * 128;
    const int col0 = (flat % nbx) * TN;
    const int moff = (TN == 128) ? (w >> 1) * 64 : w * 32;
    const int noff = (TN == 128) ? (w & 1) * 64 : 0;
    const int srow = lane >> 3;                          // 0..7 within 8-row slab
    const int scol = (((lane & 7) ^ srow) << 3);         // inverse-swizzled src col
    const int lx7  = li & 7;                             // read-side row&7

    floatx4 o[MI][4];
    #pragma unroll
    for (int i = 0; i < MI; i++)
        #pragma unroll
        for (int j = 0; j < 4; j++)
            o[i][j] = (floatx4){0.f, 0.f, 0.f, 0.f};

    for (int k0 = 0; k0 < DD; k0 += 64) {
        __syncthreads();
        #pragma unroll
        for (int i = 0; i < 4; i++) {
            const int rr = w * 32 + i * 8;
            gload_lds16(A + (size_t)(row0 + rr + srow) * DD + k0 + scol,
                        &Ash[rr * 64]);
            if (TN == 128 || w < 2) {
                const int q  = rr + srow;                // B LDS row
                const int bq = (q & ~63) | tau_pos(q & 63);  // tau src row
                gload_lds16(BT + (size_t)(col0 + bq) * DD + k0 + scol,
                            &Bsh[rr * 64]);
            }
        }
        __syncthreads();
        #pragma unroll
        for (int ks = 0; ks < 2; ks++) {
            short8 af[MI], bf[4];
            const int ch = ((ks << 2) + grp) ^ lx7;
            #pragma unroll
            for (int i = 0; i < MI; i++)
                af[i] = *(const short8*)&Ash[(moff + i * 16 + li) * 64 + ch * 8];
            #pragma unroll
            for (int j = 0; j < 4; j++)
                bf[j] = *(const short8*)&Bsh[(noff + j * 16 + li) * 64 + ch * 8];
            #pragma unroll
            for (int i = 0; i < MI; i++)
                #pragma unroll
                for (int j = 0; j < 4; j++)
                    o[i][j] = MFMA16(af[i], bf[j], o[i][j]);
        }
    }

    const bool f32 = flags[0] != 0;
    const int cbase = col0 + noff + li * 4;              // 4 consecutive cols
    float4 b4 = load4(bias, cbase, f32);
    float bv[4] = {b4.x, b4.y, b4.z, b4.w};

    #pragma unroll
    for (int i = 0; i < MI; i++) {
        #pragma unroll
        for (int r = 0; r < 4; r++) {
            int grow = row0 + moff + i * 16 + grp * 4 + r;
            float v0 = o[i][0][r] + bv[0];
            float v1 = o[i][1][r] + bv[1];
            float v2 = o[i][2][r] + bv[2];
            float v3 = o[i][3][r] + bv[3];
            if (MODE == 0) {
                uint2 pk;
                pk.x = (unsigned)f2bf(v0) | ((unsigned)f2bf(v1) << 16);
                pk.y = (unsigned)f2bf(v2) | ((unsigned)f2bf(v3) << 16);
                *(uint2*)&((unsigned short*)outp)[(size_t)grow * NCOL + cbase] = pk;
            } else {
                int b = grow / RTOT, rr2 = grow % RTOT;
                size_t dst = (rr2 < PP)
                    ? ((size_t)(b * PP + rr2) * DD + cbase)
                    : ((size_t)BS * PP * DD + (size_t)(b * NN + (rr2 - PP)) * DD + cbase);
                *(float4*)&((float*)outp)[dst] = make_float4(v0, v1, v2, v3);
            }
        }
    }
}

// ---------------------------------------------------------------------------
// fattn3 (round-8 optimum): 32 queries/wave, swapped QK^T, in-register P,
// V in LDS from sigma+tau-permuted VtG, VALU-accumulated l.
// REGION-BALANCED XCD swizzle: cross (10-tile) and self (2-tile) block
// regions are swizzled independently so every XCD gets 1/8 of EACH region
// (r12's single-region swizzle starved XCD7: occ 32->25, dur +24%), while
// the 16 q-blocks sharing one (b,h,chunk) K/V panel stay contiguous per XCD
// (FETCH 74.7 -> 23.7 MB, kept).
// ---------------------------------------------------------------------------
template<bool PACKED, int SPL>
__global__ __launch_bounds__(256, 4) void fattn3_kernel(
    const unsigned short* __restrict__ qkv,
    const unsigned short* __restrict__ VtG,      // used if PACKED
    const float* __restrict__ mb,                // log2-domain bias [BS*RTOT]
    unsigned short* __restrict__ attn_out,       // used if SPL==1
    unsigned short* __restrict__ part_o,         // used if SPL>1
    float* __restrict__ part_l)                  // used if SPL>1
{
    const int CB = BS * HH * (NN / 128);   // 384
    const int SB = BS * HH * (PP / 128);   // 96
    const int CC8 = CB * SPL / 8;          // cross blocks per XCD
    const int SC8 = SB * SPL / 8;          // self blocks per XCD

    const int xk = blockIdx.x & 7;         // XCD slot (round-robin dispatch)
    const int xj = blockIdx.x >> 3;        // position within this XCD's run
    int bid = (xj < CC8) ? (xk * CC8 + xj)
                         : (CB * SPL + xk * SC8 + (xj - CC8));
    bool cross; int chunk, v;
    if (bid < CB * SPL) { cross = true;  chunk = bid / CB; v = bid % CB; }
    else { int s = bid - CB * SPL; cross = false; chunk = s / SB; v = s % SB; }
    const int nqb  = cross ? (NN / 128) : (PP / 128);
    const int q0   = (v % nqb) * 128;
    const int h    = (v / nqb) % HH;
    const int b    = v / (nqb * HH);
    const int QOFF = cross ? PP : 0;
    const int NT   = cross ? (RTOT / 64) : (PP / 64);
    const int tpc  = NT / SPL;
    const int t_beg = chunk * tpc, t_end = chunk * tpc + tpc;
    const int rowbase = cross ? ((b * HH + h) * NN + q0)
                              : (CROWS + (b * HH + h) * PP + q0);

    alignas(16) __shared__ unsigned short Ks[64][72];
    alignas(16) __shared__ unsigned short Vt[64][72];

    const int tid  = threadIdx.x;
    const int w    = tid >> 6;
    const int lane = tid & 63;
    const int grp  = lane >> 4;
    const int li   = lane & 15;
    const int lr   = tid >> 2;
    const int ld0  = (tid & 3) << 4;

    // Q B-frags: 2 q-tiles of 16 per wave (queries q0 + w*32 + qi*16 + li)
    short8 qf[2][2];
    #pragma unroll
    for (int qi = 0; qi < 2; qi++) {
        const unsigned short* qp = qkv +
            (size_t)(b * RTOT + QOFF + q0 + w * 32 + qi * 16 + li) * QKVC
            + h * HD + grp * 8;
        qf[qi][0] = *(const short8*)(qp);
        qf[qi][1] = *(const short8*)(qp + 32);
    }

    floatx4 o[2][4];
    #pragma unroll
    for (int qi = 0; qi < 2; qi++)
        #pragma unroll
        for (int n = 0; n < 4; n++)
            o[qi][n] = (floatx4){0.f, 0.f, 0.f, 0.f};
    float lp[2] = {0.f, 0.f};   // per-lane l partial for query (lane&15)

    // ---- incremental K/V source pointers + first-tile register prefetch ----
    const unsigned short* kptr = qkv +
        (size_t)(b * RTOT + t_beg * 64 + lr) * QKVC + DD + h * HD + ld0;
    const unsigned short* vptr = PACKED
        ? VtG + ((size_t)(b * HH + h) * HD + lr) * RTOT + t_beg * 64 + ld0
        : kptr + DD;
    const float* mbp = mb + b * RTOT + t_beg * 64 + grp * 4;

    uint4 kr0, kr1, vr0, vr1;
    kr0 = ((const uint4*)kptr)[0];
    kr1 = ((const uint4*)kptr)[1];
    vr0 = ((const uint4*)vptr)[0];
    vr1 = ((const uint4*)vptr)[1];
    kptr += (size_t)64 * QKVC;
    vptr += PACKED ? 64 : (size_t)64 * QKVC;

    for (int t = t_beg; t < t_end; t++) {
        __syncthreads();   // all waves done reading Ks/Vt of previous tile
        // ---- stage from registers ----
        *(uint4*)&Ks[lr][ld0]     = kr0;
        *(uint4*)&Ks[lr][ld0 + 8] = kr1;
        if (PACKED) {
            *(uint4*)&Vt[lr][ld0]     = vr0;   // VtG already sigma+tau-permuted
            *(uint4*)&Vt[lr][ld0 + 8] = vr1;
        } else {
            unsigned short tmp[16];
            *(uint4*)&tmp[0] = vr0;
            *(uint4*)&tmp[8] = vr1;
            const int slr = sigma_pos(lr);     // key lr stored at column slr
            #pragma unroll
            for (int j = 0; j < 16; j++)
                Vt[tau_inv(ld0 + j)][slr] = tmp[j];   // dv d at row tau_inv(d)
        }
        __syncthreads();

        // ---- prefetch next tile (overlaps compute) ----
        if (t + 1 < t_end) {
            kr0 = ((const uint4*)kptr)[0];
            kr1 = ((const uint4*)kptr)[1];
            vr0 = ((const uint4*)vptr)[0];
            vr1 = ((const uint4*)vptr)[1];
            kptr += (size_t)64 * QKVC;
            vptr += PACKED ? 64 : (size_t)64 * QKVC;
        }

        // ---- S^T = K Q^T: lane holds P-row of query li, keys n*16+grp*4+r --
        floatx4 sfT[2][4];
        __builtin_amdgcn_s_setprio(1);
        #pragma unroll
        for (int n = 0; n < 4; n++) {
            short8 kb0 = *(const short8*)&Ks[n * 16 + li][grp * 8];
            short8 kb1 = *(const short8*)&Ks[n * 16 + li][32 + grp * 8];
            #pragma unroll
            for (int qi = 0; qi < 2; qi++) {
                floatx4 acc = {0.f, 0.f, 0.f, 0.f};
                acc = MFMA16(kb0, qf[qi][0], acc);
                acc = MFMA16(kb1, qf[qi][1], acc);
                sfT[qi][n] = acc;
            }
        }
        __builtin_amdgcn_s_setprio(0);

        floatx4 mbv[4];
        #pragma unroll
        for (int n = 0; n < 4; n++)
            mbv[n] = *(const floatx4*)(mbp + n * 16);
        mbp += 64;

        // ---- softmax in log2 domain; trunc-bf16 P packed in-register into
        //      the PV A-fragment (sigma key order) ----
        short8 pa[2][2];
        #pragma unroll
        for (int qi = 0; qi < 2; qi++) {
            unsigned u[4][4];
            #pragma unroll
            for (int n = 0; n < 4; n++) {
                #pragma unroll
                for (int r = 0; r < 4; r++) {
                    float e = __builtin_amdgcn_exp2f(
                        fmaf(sfT[qi][n][r], SCL2, mbv[n][r]));
                    u[n][r] = __float_as_uint(e);
                    lp[qi] += __uint_as_float(u[n][r] & 0xffff0000u);
                }
            }
            #pragma unroll
            for (int s2 = 0; s2 < 2; s2++) {
                uint4 pk;
                pk.x = __builtin_amdgcn_perm(u[2*s2][1],   u[2*s2][0],   0x07060302u);
                pk.y = __builtin_amdgcn_perm(u[2*s2][3],   u[2*s2][2],   0x07060302u);
                pk.z = __builtin_amdgcn_perm(u[2*s2+1][1], u[2*s2+1][0], 0x07060302u);
                pk.w = __builtin_amdgcn_perm(u[2*s2+1][3], u[2*s2+1][2], 0x07060302u);
                pa[qi][s2] = __builtin_bit_cast(short8, pk);
            }
        }

        // ---- O += P V (P in registers; O slot n2 = true dv li*4+n2) ----
        __builtin_amdgcn_s_setprio(1);
        #pragma unroll
        for (int s2 = 0; s2 < 2; s2++) {
            #pragma unroll
            for (int n2 = 0; n2 < 4; n2++) {
                short8 vf = *(const short8*)&Vt[n2 * 16 + li][s2 * 32 + grp * 8];
                o[0][n2] = MFMA16(pa[0][s2], vf, o[0][n2]);
                o[1][n2] = MFMA16(pa[1][s2], vf, o[1][n2]);
            }
        }
        __builtin_amdgcn_s_setprio(0);
    }

    // ---- l reduction: sum the 4 grp-partials for each query ----
    float lfull[2];
    #pragma unroll
    for (int qi = 0; qi < 2; qi++) {
        float l = lp[qi];
        l += __shfl_xor(l, 16);
        l += __shfl_xor(l, 32);
        lfull[qi] = l;    // value for query (lane&15), replicated across grps
    }

    // ---- epilogue: dv of o[qi][n2][r] is li*4+n2 -> packed uint2 stores ----
    if (SPL > 1) {
        #pragma unroll
        for (int qi = 0; qi < 2; qi++)
            #pragma unroll
            for (int r = 0; r < 4; r++) {
                float lv = __shfl(lfull[qi], grp * 4 + r);
                size_t row = (size_t)chunk * TROWS + rowbase
                           + w * 32 + qi * 16 + grp * 4 + r;
                uint2 pk;
                pk.x = (unsigned)f2bf(o[qi][0][r]) | ((unsigned)f2bf(o[qi][1][r]) << 16);
                pk.y = (unsigned)f2bf(o[qi][2][r]) | ((unsigned)f2bf(o[qi][3][r]) << 16);
                *(uint2*)&part_o[row * 64 + li * 4] = pk;
                if (li == 0) part_l[row] = lv;
            }
    } else {
        #pragma unroll
        for (int qi = 0; qi < 2; qi++)
            #pragma unroll
            for (int r = 0; r < 4; r++) {
                float inv = 1.0f / __shfl(lfull[qi], grp * 4 + r);
                int qloc = q0 + w * 32 + qi * 16 + grp * 4 + r;
                if (cross) {
                    size_t row = (size_t)(b * RTOT + PP + qloc);
                    uint2 pk;
                    pk.x = (unsigned)f2bf(o[qi][0][r] * inv)
                         | ((unsigned)f2bf(o[qi][1][r] * inv) << 16);
                    pk.y = (unsigned)f2bf(o[qi][2][r] * inv)
                         | ((unsigned)f2bf(o[qi][3][r] * inv) << 16);
                    *(uint2*)&attn_out[row * DD + h * HD + li * 4] = pk;
                } else {
                    #pragma unroll
                    for (int n2 = 0; n2 < 4; n2++) {
                        int dc = li * 4 + n2;
                        int f = h * (HD * PP) + dc * PP + qloc;
                        attn_out[(size_t)(b * RTOT + f / DD) * DD + (f % DD)]
                            = f2bf(o[qi][n2][r] * inv);
                    }
                }
            }
    }
}

// ---------------------------------------------------------------------------
// Split-K combine. Cross rows: contiguous writes. Self rows: 64-row LDS
// transpose -> contiguous 32B writes.
// ---------------------------------------------------------------------------
template<int SPL>
__global__ __launch_bounds__(256) void combine_kernel(
    const unsigned short* __restrict__ part_o,
    const float* __restrict__ part_l,
    unsigned short* __restrict__ attn_out)
{
    const int CBLK = CROWS / 4;            // 12288
    if (blockIdx.x < CBLK) {
        const int row = blockIdx.x * 4 + (threadIdx.x >> 6);
        const int dv  = threadIdx.x & 63;
        float l = 0.f, ov = 0.f;
        #pragma unroll
        for (int c = 0; c < SPL; c++) {
            l  += part_l[(size_t)c * TROWS + row];
            ov += bf2f(part_o[((size_t)c * TROWS + row) * 64 + dv]);
        }
        float res = ov / l;
        int b = row / (HH * NN), rem = row % (HH * NN);
        int h = rem / NN, n = rem % NN;
        attn_out[(size_t)(b * RTOT + PP + n) * DD + h * HD + dv] = f2bf(res);
        return;
    }
    // ---- self rows: 64 rows/block, transpose in LDS ----
    __shared__ unsigned short T[64][72];
    const int blk = blockIdx.x - CBLK;     // 0..SROWS/64-1
    const int r0b = blk * 64;              // offset into self region
    {
        const int rp  = threadIdx.x >> 2;          // row in group
        const int d0  = (threadIdx.x & 3) * 16;
        const int row = CROWS + r0b + rp;
        float l = 0.f;
        float ov[16] = {};
        #pragma unroll
        for (int c = 0; c < SPL; c++) {
            l += part_l[(size_t)c * TROWS + row];
            const uint4* po = (const uint4*)&part_o[((size_t)c * TROWS + row) * 64 + d0];
            uint4 x0 = po[0], x1 = po[1];
            const unsigned short* u0 = (const unsigned short*)&x0;
            const unsigned short* u1 = (const unsigned short*)&x1;
            #pragma unroll
            for (int k = 0; k < 8; k++) { ov[k] += bf2f(u0[k]); ov[8 + k] += bf2f(u1[k]); }
        }
        float inv = 1.0f / l;
        #pragma unroll
        for (int k = 0; k < 16; k++) T[rp][d0 + k] = f2bf(ov[k] * inv);
    }
    __syncthreads();
    {
        const int dv = threadIdx.x >> 2;
        const int pc = (threadIdx.x & 3) * 16;
        const int bh = r0b / PP;           // b*HH + h
        const int p0 = r0b % PP;
        const int b = bh / HH, h = bh % HH;
        unsigned short tmp[16];
        #pragma unroll
        for (int k = 0; k < 16; k++) tmp[k] = T[pc + k][dv];
        size_t base = (size_t)b * RTOT * DD + (size_t)h * (HD * PP)
                    + (size_t)dv * PP + p0 + pc;
        *(uint4*)&attn_out[base]     = *(uint4*)&tmp[0];
        *(uint4*)&attn_out[base + 8] = *(uint4*)&tmp[8];
    }
}

// ---------------------------------------------------------------------------
// Round-9 fattn (fallback tier, online softmax, reads mask directly).
// ---------------------------------------------------------------------------
template<int MODE>
__global__ __launch_bounds__(256) void fattn_kernel(
    const __hip_bfloat16* __restrict__ qkv,
    const void* __restrict__ mask,
    const int* __restrict__ flags,
    __hip_bfloat16* __restrict__ attn_out)
{
    constexpr int NQ    = (MODE == 0) ? NN : PP;
    constexpr int NK    = (MODE == 0) ? RTOT : PP;
    constexpr int QOFF  = (MODE == 0) ? PP : 0;
    constexpr int NTILE = NK / 64;

    alignas(16) __shared__ unsigned short Ks[64][72];
    alignas(16) __shared__ unsigned short Vt[64][72];
    alignas(16) __shared__ unsigned short Psm[4][16][72];

    const int tid   = threadIdx.x;
    const int w     = tid >> 6;
    const int lane  = tid & 63;
    const int grp   = lane >> 4;
    const int li    = lane & 15;
    const int nqb   = NQ / 64;
    const int q0    = (blockIdx.x % nqb) * 64;
    const int h     = (blockIdx.x / nqb) % HH;
    const int b     = blockIdx.x / (nqb * HH);
    const int mtype = flags[1];

    const unsigned short* qkv_u = (const unsigned short*)qkv;
    const int lr  = tid >> 2;
    const int ld0 = (tid & 3) << 4;

    short8 qf[2];
    {
        const unsigned short* qp = qkv_u +
            (size_t)(b * RTOT + QOFF + q0 + w * 16 + li) * QKVC + h * HD + grp * 8;
        qf[0] = *(const short8*)(qp);
        qf[1] = *(const short8*)(qp + 32);
    }

    floatx4 o[4] = {{0.f,0.f,0.f,0.f},{0.f,0.f,0.f,0.f},
                    {0.f,0.f,0.f,0.f},{0.f,0.f,0.f,0.f}};
    float mrun[4] = {-3e38f, -3e38f, -3e38f, -3e38f};
    float lrun[4] = {0.f, 0.f, 0.f, 0.f};

    for (int t = 0; t < NTILE; t++) {
        const int m0 = t * 64;
        __syncthreads();
        {
            const unsigned short* kp = qkv_u +
                (size_t)(b * RTOT + m0 + lr) * QKVC + DD + h * HD + ld0;
            *(uint4*)&Ks[lr][ld0]     = ((const uint4*)kp)[0];
            *(uint4*)&Ks[lr][ld0 + 8] = ((const uint4*)kp)[1];
            const unsigned short* vp = kp + DD;
            unsigned short tmp[16];
            *(uint4*)&tmp[0] = ((const uint4*)vp)[0];
            *(uint4*)&tmp[8] = ((const uint4*)vp)[1];
            #pragma unroll
            for (int j = 0; j < 16; j++) Vt[ld0 + j][lr] = tmp[j];
        }
        __syncthreads();

        floatx4 sf[4];
        #pragma unroll
        for (int n = 0; n < 4; n++) {
            floatx4 acc = {0.f, 0.f, 0.f, 0.f};
            short8 kb0 = *(const short8*)&Ks[n * 16 + li][grp * 8];
            short8 kb1 = *(const short8*)&Ks[n * 16 + li][32 + grp * 8];
            acc = MFMA16(qf[0], kb0, acc);
            acc = MFMA16(qf[1], kb1, acc);
            sf[n] = acc;
        }

        bool mk[4];
        #pragma unroll
        for (int n = 0; n < 4; n++) {
            int m = m0 + n * 16 + li;
            mk[n] = (m < PP) && mask_at(mask, b * PP + m, mtype);
        }

        #pragma unroll
        for (int r = 0; r < 4; r++) {
            float sv[4];
            #pragma unroll
            for (int n = 0; n < 4; n++)
                sv[n] = mk[n] ? -1e30f : sf[n][r] * 0.125f;
            float tm = fmaxf(fmaxf(sv[0], sv[1]), fmaxf(sv[2], sv[3]));
            #pragma unroll
            for (int off = 1; off < 16; off <<= 1)
                tm = fmaxf(tm, __shfl_xor(tm, off));
            float mnew = fmaxf(mrun[r], tm);
            float al = __expf(mrun[r] - mnew);
            float p[4], ts = 0.f;
            #pragma unroll
            for (int n = 0; n < 4; n++) {
                p[n] = (sv[n] < -1e29f) ? 0.f : __expf(sv[n] - mnew);
                ts += p[n];
            }
            #pragma unroll
            for (int off = 1; off < 16; off <<= 1)
                ts += __shfl_xor(ts, off);
            mrun[r] = mnew;
            lrun[r] = lrun[r] * al + ts;
            #pragma unroll
            for (int n = 0; n < 4; n++) {
                o[n][r] *= al;
                Psm[w][grp * 4 + r][n * 16 + li] = f2bf(p[n]);
            }
        }
        __syncthreads();

        #pragma unroll
        for (int s2 = 0; s2 < 2; s2++) {
            short8 pa = *(const short8*)&Psm[w][li][s2 * 32 + grp * 8];
            #pragma unroll
            for (int n2 = 0; n2 < 4; n2++) {
                short8 vf = *(const short8*)&Vt[n2 * 16 + li][s2 * 32 + grp * 8];
                o[n2] = MFMA16(pa, vf, o[n2]);
            }
        }
    }

    unsigned short* ao = (unsigned short*)attn_out;
    #pragma unroll
    for (int r = 0; r < 4; r++) {
        float inv = 1.0f / lrun[r];
        int qloc = q0 + w * 16 + grp * 4 + r;
        if (MODE == 0) {
            size_t row = (size_t)(b * RTOT + PP + qloc);
            #pragma unroll
            for (int n2 = 0; n2 < 4; n2++)
                ao[row * DD + h * HD + n2 * 16 + li] = f2bf(o[n2][r] * inv);
        } else {
            #pragma unroll
            for (int n2 = 0; n2 < 4; n2++) {
                int dc = n2 * 16 + li;
                int f = h * (HD * PP) + dc * PP + qloc;
                ao[(size_t)(b * RTOT + f / DD) * DD + (f % DD)] = f2bf(o[n2][r] * inv);
            }
        }
    }
}

// ---------------------------------------------------------------------------
// Vector GEMM fallback (last-resort tier).
// ---------------------------------------------------------------------------
template<int MODE, int NCOL, typename OutT>
__global__ __launch_bounds__(256) void gemm_kernel(
    const void* __restrict__ A0, const void* __restrict__ A1,
    const void* __restrict__ W, const void* __restrict__ bias,
    const int* __restrict__ flags, OutT* __restrict__ out)
{
    const bool f32 = flags[0] != 0;
    alignas(16) __shared__ float As[16][68];
    alignas(16) __shared__ float Bsh2[16][68];
    const int tid  = threadIdx.x;
    const int row0 = blockIdx.y * 64;
    const int col0 = blockIdx.x * 64;
    const int ty = tid >> 4, tx = tid & 15;
    const int a_row = tid >> 2;
    const int a_k4  = (tid & 3) * 4;
    const int grow  = row0 + a_row;
    const void* abase; size_t aoff; bool af32;
    if (MODE == 0) {
        int b = grow / RTOT, r = grow % RTOT;
        if (r < NN) { abase = A0; aoff = (size_t)(b * NN + r) * DD; }
        else        { abase = A1; aoff = (size_t)(b * PP + (r - NN)) * DD; }
        af32 = f32;
    } else {
        abase = A0; aoff = (size_t)grow * DD; af32 = false;
    }
    const int b_k  = tid >> 4;
    const int b_n4 = (tid & 15) * 4;
    float acc[4][4] = {};
    for (int k0 = 0; k0 < DD; k0 += 16) {
        float4 fa = load4(abase, aoff + k0 + a_k4, af32);
        As[a_k4 + 0][a_row] = fa.x;
        As[a_k4 + 1][a_row] = fa.y;
        As[a_k4 + 2][a_row] = fa.z;
        As[a_k4 + 3][a_row] = fa.w;
        float4 fb = load4(W, (size_t)(k0 + b_k) * NCOL + col0 + b_n4, f32);
        *(float4*)&Bsh2[b_k][b_n4] = fb;
        __syncthreads();
        #pragma unroll
        for (int kk = 0; kk < 16; kk++) {
            float4 av = *(const float4*)&As[kk][ty * 4];
            float4 bvv = *(const float4*)&Bsh2[kk][tx * 4];
            float a_[4] = {av.x, av.y, av.z, av.w};
            float b_[4] = {bvv.x, bvv.y, bvv.z, bvv.w};
            #pragma unroll
            for (int i = 0; i < 4; i++)
                #pragma unroll
                for (int j = 0; j < 4; j++)
                    acc[i][j] += a_[i] * b_[j];
        }
        __syncthreads();
    }
    #pragma unroll
    for (int i = 0; i < 4; i++) {
        int gr = row0 + ty * 4 + i;
        #pragma unroll
        for (int j = 0; j < 4; j++) {
            int gc = col0 + tx * 4 + j;
            float v = acc[i][j] + load1(bias, gc, f32);
            if (MODE == 0) {
                store_out(out, (size_t)gr * NCOL + gc, v);
            } else {
                int b = gr / RTOT, r = gr % RTOT;
                size_t dst = (r < PP)
                    ? ((size_t)(b * PP + r) * DD + gc)
                    : ((size_t)BS * PP * DD + (size_t)(b * NN + (r - PP)) * DD + gc);
                store_out(out, dst, v);
            }
        }
    }
}

// ---------------------------------------------------------------------------
extern "C" void kernel_launch(void* const* d_in, const int* in_sizes, int n_in,
                              void* d_out, int out_size, void* d_ws, size_t ws_size,
                              hipStream_t stream) {
    const void *xs = nullptr, *xq = nullptr, *mask = nullptr,
               *qkv_w = nullptr, *qkv_b = nullptr, *proj_w = nullptr, *proj_b = nullptr;
    for (int i = 0; i < n_in; i++) {
        switch (in_sizes[i]) {
            case BS * PP * DD:   xs     = d_in[i]; break;
            case BS * NN * DD:   xq     = d_in[i]; break;
            case BS * PP:        mask   = d_in[i]; break;
            case DD * QKVC:      qkv_w  = d_in[i]; break;
            case QKVC:           qkv_b  = d_in[i]; break;
            case DD * DD:        proj_w = d_in[i]; break;
            case DD:             proj_b = d_in[i]; break;
        }
    }
    if (!xs || !xq || !mask || !qkv_w || !qkv_b || !proj_w || !proj_b) {
        xs = d_in[0]; xq = d_in[1]; mask = d_in[2];
        qkv_w = d_in[3]; qkv_b = d_in[4]; proj_w = d_in[5]; proj_b = d_in[6];
    }
    float* out = (float*)d_out;

    const size_t off_mb   = 256;
    const size_t off_full = off_mb   + (size_t)BS * RTOT * 4;
    const size_t off_ab   = off_full + (size_t)MTOT * QKVC * 2;
    const size_t off_w    = off_ab   + (size_t)MTOT * DD * 2;
    const size_t off_wp   = off_w    + (size_t)QKVC * DD * 2;
    const size_t off_vt   = off_wp   + (size_t)DD * DD * 2;
    const size_t off_po   = off_vt   + (size_t)BS * HH * HD * RTOT * 2;
    // SPL=4 tier
    const size_t off_ml4  = off_po   + (size_t)4 * TROWS * 64 * 2;
    const size_t need_A4  = off_ml4  + (size_t)4 * TROWS * 4;
    // SPL=2 tier
    const size_t off_ml2  = off_po   + (size_t)2 * TROWS * 64 * 2;
    const size_t need_A2  = off_ml2  + (size_t)2 * TROWS * 4;
    const size_t need_B   = off_po;
    const size_t need_C   = off_vt;

    const size_t r_full = 256;
    const size_t r_ab   = r_full + (size_t)MTOT * QKVC * 2;
    const size_t r_wq   = r_ab   + (size_t)MTOT * DD * 2;
    const size_t r_wp   = r_wq   + (size_t)QKVC * DD * 2;
    const size_t need_R = r_wp   + (size_t)DD * DD * 2;

    int* flags = (int*)d_ws;
    const int NCMB = CROWS / 4 + SROWS / 64;   // combine grid

    if (ws_size >= need_C) {
        float* mb               = (float*)((char*)d_ws + off_mb);
        unsigned short* fullqkv = (unsigned short*)((char*)d_ws + off_full);
        unsigned short* attn    = (unsigned short*)((char*)d_ws + off_ab);
        unsigned short* WqkvT   = (unsigned short*)((char*)d_ws + off_w);
        unsigned short* WprojT  = (unsigned short*)((char*)d_ws + off_wp);
        unsigned short* VtG     = (unsigned short*)((char*)d_ws + off_vt);
        unsigned short* part_o  = (unsigned short*)((char*)d_ws + off_po);

        detect_kernel<<<1, 256, 0, stream>>>(qkv_w, mask, flags, mb, 1);
        prep_kernel<<<MTOT + TQKV + TPRJ, 256, 0, stream>>>(
            xq, xs, qkv_w, proj_w, flags, attn /*as Abf*/, WqkvT, WprojT);

        mgemm_kernel<0, QKVC, 128><<<dim3(QKVC / 128, MTOT / 128), 256, 0, stream>>>(
            attn /*Abf*/, WqkvT, qkv_b, flags, (void*)fullqkv);

        const int CB = BS * HH * (NN / 128), SB = BS * HH * (PP / 128);
        if (ws_size >= need_A4) {
            float* part_l = (float*)((char*)d_ws + off_ml4);
            vtprep_kernel<<<dim3(RTOT / 64, BS * HH), 256, 0, stream>>>(fullqkv, VtG);
            fattn3_kernel<true, 4><<<(CB + SB) * 4, 256, 0, stream>>>(
                fullqkv, VtG, mb, nullptr, part_o, part_l);
            combine_kernel<4><<<NCMB, 256, 0, stream>>>(part_o, part_l, attn);
        } else if (ws_size >= need_A2) {
            float* part_l = (float*)((char*)d_ws + off_ml2);
            vtprep_kernel<<<dim3(RTOT / 64, BS * HH), 256, 0, stream>>>(fullqkv, VtG);
            fattn3_kernel<true, 2><<<(CB + SB) * 2, 256, 0, stream>>>(
                fullqkv, VtG, mb, nullptr, part_o, part_l);
            combine_kernel<2><<<NCMB, 256, 0, stream>>>(part_o, part_l, attn);
        } else if (ws_size >= need_B) {
            vtprep_kernel<<<dim3(RTOT / 64, BS * HH), 256, 0, stream>>>(fullqkv, VtG);
            fattn3_kernel<true, 1><<<CB + SB, 256, 0, stream>>>(
                fullqkv, VtG, mb, attn, nullptr, nullptr);
        } else {
            fattn3_kernel<false, 1><<<CB + SB, 256, 0, stream>>>(
                fullqkv, nullptr, mb, attn, nullptr, nullptr);
        }

        mgemm_kernel<1, DD, 64><<<dim3(DD / 64, MTOT / 128), 256, 0, stream>>>(
            attn, WprojT, proj_b, flags, (void*)out);
    } else if (ws_size >= need_R) {
        unsigned short* fullqkv = (unsigned short*)((char*)d_ws + r_full);
        unsigned short* attn    = (unsigned short*)((char*)d_ws + r_ab);
        unsigned short* WqkvT   = (unsigned short*)((char*)d_ws + r_wq);
        unsigned short* WprojT  = (unsigned short*)((char*)d_ws + r_wp);

        detect_kernel<<<1, 256, 0, stream>>>(qkv_w, mask, flags, nullptr, 0);
        prep_kernel<<<MTOT + TQKV + TPRJ, 256, 0, stream>>>(
            xq, xs, qkv_w, proj_w, flags, attn, WqkvT, WprojT);
        mgemm_kernel<0, QKVC, 128><<<dim3(QKVC / 128, MTOT / 128), 256, 0, stream>>>(
            attn, WqkvT, qkv_b, flags, (void*)fullqkv);
        fattn_kernel<0><<<BS * HH * (NN / 64), 256, 0, stream>>>(
            (const __hip_bfloat16*)fullqkv, mask, flags, (__hip_bfloat16*)attn);
        fattn_kernel<1><<<BS * HH * (PP / 64), 256, 0, stream>>>(
            (const __hip_bfloat16*)fullqkv, mask, flags, (__hip_bfloat16*)attn);
        mgemm_kernel<1, DD, 64><<<dim3(DD / 64, MTOT / 128), 256, 0, stream>>>(
            attn, WprojT, proj_b, flags, (void*)out);
    } else {
        __hip_bfloat16* fullqkv = (__hip_bfloat16*)((char*)d_ws + 256);
        __hip_bfloat16* attn    = fullqkv + (size_t)MTOT * QKVC;
        detect_kernel<<<1, 256, 0, stream>>>(qkv_w, mask, flags, nullptr, 0);
        gemm_kernel<0, QKVC, __hip_bfloat16>
            <<<dim3(QKVC / 64, MTOT / 64), 256, 0, stream>>>(
            xq, xs, qkv_w, qkv_b, flags, fullqkv);
        fattn_kernel<0><<<BS * HH * (NN / 64), 256, 0, stream>>>(fullqkv, mask, flags, attn);
        fattn_kernel<1><<<BS * HH * (PP / 64), 256, 0, stream>>>(fullqkv, mask, flags, attn);
        gemm_kernel<1, DD, float>
            <<<dim3(DD / 64, MTOT / 64), 256, 0, stream>>>(
            attn, nullptr, proj_w, proj_b, flags, out);
    }
}

// Round 14
// 179.835 us; speedup vs baseline: 1.0944x; 1.0410x over previous
//
#include <hip/hip_runtime.h>
#include <hip/hip_bf16.h>

#define BS   2
#define PP   512
#define NN   2048
#define DD   768
#define HH   12
#define HD   64
#define RTOT 2560   // P + N rows per batch
#define QKVC 2304   // 3*D
#define MTOT (BS * RTOT)       // 5120
#define CROWS (BS * HH * NN)   // 49152 cross q-rows
#define SROWS (BS * HH * PP)   // 12288 self q-rows
#define TROWS (CROWS + SROWS)  // 61440

typedef __attribute__((ext_vector_type(8))) short  short8;
typedef __attribute__((ext_vector_type(4))) float  floatx4;

#define MFMA16(a, b, c) __builtin_amdgcn_mfma_f32_16x16x32_bf16(a, b, c, 0, 0, 0)
#define LOG2E 1.4426950408889634f
#define SCL2  0.18033688011112042f   // 0.125 * log2(e)

__device__ __forceinline__ float bf2f(unsigned short x) {
    union { unsigned u; float f; } c; c.u = ((unsigned)x) << 16; return c.f;
}
__device__ __forceinline__ unsigned short f2bf(float x) {
    union { float f; unsigned u; } c; c.f = x;
    unsigned r = c.u + 0x7fff + ((c.u >> 16) & 1);   // RNE
    return (unsigned short)(r >> 16);
}

__device__ __forceinline__ float4 load4(const void* p, size_t i, bool f32) {
    if (f32) return *(const float4*)((const float*)p + i);
    ushort4 u = *(const ushort4*)((const unsigned short*)p + i);
    return make_float4(bf2f(u.x), bf2f(u.y), bf2f(u.z), bf2f(u.w));
}
__device__ __forceinline__ float load1(const void* p, size_t i, bool f32) {
    return f32 ? ((const float*)p)[i] : bf2f(((const unsigned short*)p)[i]);
}
__device__ __forceinline__ bool mask_at(const void* m, int idx, int mtype) {
    if (mtype == 2) return ((const float*)m)[idx] != 0.0f;
    if (mtype == 1) return ((const unsigned char*)m)[idx] != 0;
    return ((const int*)m)[idx] != 0;
}
__device__ __forceinline__ void store_out(float* p, size_t i, float v) { p[i] = v; }
__device__ __forceinline__ void store_out(__hip_bfloat16* p, size_t i, float v) {
    p[i] = __float2bfloat16(v);
}

// async global->LDS, 16B per lane; LDS dest = wave-uniform base + lane*16
__device__ __forceinline__ void gload_lds16(const unsigned short* g, unsigned short* l) {
    __builtin_amdgcn_global_load_lds(
        (const __attribute__((address_space(1))) void*)g,
        (__attribute__((address_space(3))) void*)l,
        16, 0, 0);
}

// XCD-aware block swizzle (T1): uniform-cost grids (mgemm). nwg % 8 == 0.
__device__ __forceinline__ int xcd_swz(int bid, int nwg) {
    return (bid & 7) * (nwg >> 3) + (bid >> 3);
}

// key-position permutation sigma: key bits [n1,n0,g1,g0,r1,r0] stored at
// position [n1,g1,g0,n0,r1,r0].
__device__ __forceinline__ int sigma_pos(int k) {
    return (k & 0x23) | ((k & 0x0C) << 1) | ((k & 0x10) >> 2);
}
__device__ __forceinline__ int sigma_inv(int p) {
    return (p & 0x23) | ((p & 0x18) >> 1) | ((p & 0x04) << 2);
}
// column/dv permutation tau within 64-groups: fragment position p = j*16+li
// holds true column tau(p) = li*4 + j.
__device__ __forceinline__ int tau_pos(int p) {
    return ((p & 15) << 2) | ((p >> 4) & 3);
}
__device__ __forceinline__ int tau_inv(int c) {
    return ((c & 3) << 4) | ((c >> 2) & 15);
}

// block-local f32 detection on w's first 16KB: if w is f32, reinterpreted
// bf16 halves trip |v|>2 <=> (h&0x7fff)+0x3fff carries into bit15.
__device__ __forceinline__ unsigned detect_acc(const void* w, int tid) {
    const uint4* u4 = (const uint4*)w;
    unsigned acc = 0;
    #pragma unroll
    for (int k = 0; k < 4; k++) {
        uint4 x = u4[k * 256 + tid];
        unsigned t0 = x.x & 0x7fff7fffu, t1 = x.y & 0x7fff7fffu;
        unsigned t2 = x.z & 0x7fff7fffu, t3 = x.w & 0x7fff7fffu;
        acc |= (t0 + 0x3fff3fffu) & 0x80008000u;
        acc |= (t1 + 0x3fff3fffu) & 0x80008000u;
        acc |= (t2 + 0x3fff3fffu) & 0x80008000u;
        acc |= (t3 + 0x3fff3fffu) & 0x80008000u;
    }
    return acc;
}

// ---------------------------------------------------------------------------
// Runtime dtype detection (fallback tiers only; main tier self-detects).
// ---------------------------------------------------------------------------
__global__ void detect_kernel(const void* __restrict__ w,
                              const void* __restrict__ mask,
                              int* __restrict__ flags,
                              float* __restrict__ mb, int do_mb) {
    __shared__ int s_f32, s_fmask, s_bmask;
    if (threadIdx.x == 0) { s_f32 = 0; s_fmask = 0; s_bmask = 0; }
    __syncthreads();
    unsigned acc = detect_acc(w, threadIdx.x);
    if (acc) atomicOr(&s_f32, 1);
    const unsigned* mw = (const unsigned*)mask;
    int fm = 0, bm = 0;
    {
        unsigned v = mw[threadIdx.x];
        if (v == 0x3F800000u) fm = 1;
        else if ((v & 0xFFFFFF00u) != 0u) bm = 1;
    }
    if (fm) atomicOr(&s_fmask, 1);
    if (bm) atomicOr(&s_bmask, 1);
    __syncthreads();
    if (threadIdx.x == 0) {
        flags[0] = s_f32;
        flags[1] = s_fmask ? 2 : (s_bmask ? 1 : 0);
    }
    if (do_mb) {
        const int mtype = s_fmask ? 2 : (s_bmask ? 1 : 0);
        for (int i = threadIdx.x; i < BS * RTOT; i += 256) {
            int b = i / RTOT, m = i % RTOT;
            float v = -15.0f * LOG2E;
            if (m < PP && mask_at(mask, b * PP + m, mtype)) v = -1e30f;
            mb[i] = v;
        }
    }
}

// ---------------------------------------------------------------------------
// Fused prep (self-detecting; no upstream detect kernel in main tier):
// block 0: flags + mb table; blocks [1, 1+MTOT/4): concat+convert, 4 rows
// each, all 256 threads; then Wqkv / Wproj transpose tiles.
// ---------------------------------------------------------------------------
#define CBL  (MTOT / 4)                  // 1280 concat blocks
#define TQKV ((QKVC / 64) * (DD / 64))   // 432
#define TPRJ ((DD / 64) * (DD / 64))     // 144
__global__ __launch_bounds__(256) void prep_kernel(
    const void* __restrict__ xq, const void* __restrict__ xs,
    const void* __restrict__ qkv_w, const void* __restrict__ proj_w,
    const void* __restrict__ mask,
    int* __restrict__ flags, float* __restrict__ mb,
    unsigned short* __restrict__ Abf,
    unsigned short* __restrict__ WqkvT,
    unsigned short* __restrict__ WprojT)
{
    __shared__ int s_f32;
    if (threadIdx.x == 0) s_f32 = 0;
    __syncthreads();
    if (detect_acc(qkv_w, threadIdx.x)) atomicOr(&s_f32, 1);
    __syncthreads();
    const bool f32 = s_f32 != 0;

    int blk = blockIdx.x;
    if (blk == 0) {
        // ---- head: flags + log2-domain mask bias table ----
        __shared__ int s_fmask, s_bmask;
        if (threadIdx.x == 0) { s_fmask = 0; s_bmask = 0; }
        __syncthreads();
        {
            unsigned v = ((const unsigned*)mask)[threadIdx.x];
            if (v == 0x3F800000u) atomicOr(&s_fmask, 1);
            else if ((v & 0xFFFFFF00u) != 0u) atomicOr(&s_bmask, 1);
        }
        __syncthreads();
        const int mtype = s_fmask ? 2 : (s_bmask ? 1 : 0);
        if (threadIdx.x == 0) { flags[0] = f32 ? 1 : 0; flags[1] = mtype; }
        if (mb) {
            for (int i = threadIdx.x; i < BS * RTOT; i += 256) {
                int b = i / RTOT, m = i % RTOT;
                float v = -15.0f * LOG2E;
                if (m < PP && mask_at(mask, b * PP + m, mtype)) v = -1e30f;
                mb[i] = v;
            }
        }
        return;
    }
    blk -= 1;
    if (blk < CBL) {
        // ---- concat+convert: 4 rows/block, thread handles 3 float4s ----
        #pragma unroll
        for (int jj = 0; jj < 3; jj++) {
            const int gid = jj * 256 + threadIdx.x;   // 0..767
            const int r   = blk * 4 + gid / 192;
            const int c4  = gid % 192;
            const int b = r / RTOT, rr = r % RTOT;
            const void* src;
            size_t off;
            if (rr < NN) { src = xq; off = (size_t)(b * NN + rr) * DD; }
            else         { src = xs; off = (size_t)(b * PP + (rr - NN)) * DD; }
            float4 v = load4(src, off + c4 * 4, f32);
            ushort4 o;
            o.x = f2bf(v.x); o.y = f2bf(v.y); o.z = f2bf(v.z); o.w = f2bf(v.w);
            *(ushort4*)&Abf[(size_t)r * DD + c4 * 4] = o;
        }
        return;
    }
    blk -= CBL;
    __shared__ unsigned short T[64][65];
    const void* in; int R, C; unsigned short* out; int bx, by;
    if (blk < TQKV) {
        in = qkv_w; R = DD; C = QKVC; out = WqkvT;
        bx = blk % (QKVC / 64); by = blk / (QKVC / 64);
    } else {
        blk -= TQKV;
        in = proj_w; R = DD; C = DD; out = WprojT;
        bx = blk % (DD / 64); by = blk / (DD / 64);
    }
    const int c0 = bx * 64, r0 = by * 64;
    const int col = threadIdx.x & 63;
    const int r4  = threadIdx.x >> 6;
    #pragma unroll
    for (int p = 0; p < 16; p++) {
        int row = p * 4 + r4;
        T[row][col] = f2bf(load1(in, (size_t)(r0 + row) * C + c0 + col, f32));
    }
    __syncthreads();
    #pragma unroll
    for (int p = 0; p < 16; p++) {
        int crow = p * 4 + r4;
        out[(size_t)(c0 + crow) * R + r0 + col] = T[col][crow];
    }
}

// ---------------------------------------------------------------------------
// Prep: VtG[(b*HH+h)][rho][m] bf16 = V^T per head, keys sigma-permuted per
// 64-tile, dv-rows tau-permuted.
// ---------------------------------------------------------------------------
__global__ __launch_bounds__(256) void vtprep_kernel(
    const unsigned short* __restrict__ qkv, unsigned short* __restrict__ VtG)
{
    alignas(16) __shared__ unsigned short T[64][72];
    const int mt = blockIdx.x * 64;
    const int bh = blockIdx.y;
    const int b = bh / HH, h = bh % HH;
    const int lr  = threadIdx.x >> 2;
    const int ld0 = (threadIdx.x & 3) << 4;
    const unsigned short* vp = qkv +
        (size_t)(b * RTOT + mt + lr) * QKVC + 2 * DD + h * HD + ld0;
    *(uint4*)&T[lr][ld0]     = ((const uint4*)vp)[0];
    *(uint4*)&T[lr][ld0 + 8] = ((const uint4*)vp)[1];
    __syncthreads();
    const int tdv = tau_pos(lr);               // dv held by this VtG row
    unsigned short tmp[16];
    #pragma unroll
    for (int j = 0; j < 16; j++) {
        const int c = ld0 + j;                 // key storage position
        tmp[j] = T[sigma_inv(c)][tdv];         // V[key sigma_inv(c)][dv tau(lr)]
    }
    unsigned short* dst = VtG + ((size_t)bh * HD + lr) * RTOT + mt + ld0;
    *(uint4*)dst       = *(uint4*)&tmp[0];
    *(uint4*)(dst + 8) = *(uint4*)&tmp[8];
}

// ---------------------------------------------------------------------------
// MFMA GEMM: C[M=128][TN] per block = A @ BT^T + bias.
// global_load_lds staging, linear LDS, XOR chunk swizzle (both-sides).
// B N-columns tau-permuted; XCD-swizzled block mapping (uniform cost).
// ---------------------------------------------------------------------------
template<int MODE, int NCOL, int TN>
__global__ __launch_bounds__(256) void mgemm_kernel(
    const unsigned short* __restrict__ A,
    const unsigned short* __restrict__ BT,
    const void* __restrict__ bias,
    const int* __restrict__ flags,
    void* __restrict__ outp)
{
    constexpr int MI = (TN == 128) ? 4 : 2;   // 16-row m-frags per wave
    alignas(16) __shared__ unsigned short Ash[128 * 64];
    alignas(16) __shared__ unsigned short Bsh[TN * 64];

    const int tid  = threadIdx.x;
    const int w    = tid >> 6;
    const int lane = tid & 63;
    const int grp  = lane >> 4;
    const int li   = lane & 15;
    const int nbx  = gridDim.x;
    int flat = xcd_swz(blockIdx.y * nbx + blockIdx.x, nbx * gridDim.y);
    const int row0 = (flat / nbx) * 128;
    const int col0 = (flat % nbx) * TN;
    const int moff = (TN == 128) ? (w >> 1) * 64 : w * 32;
    const int noff = (TN == 128) ? (w & 1) * 64 : 0;
    const int srow = lane >> 3;                          // 0..7 within 8-row slab
    const int scol = (((lane & 7) ^ srow) << 3);         // inverse-swizzled src col
    const int lx7  = li & 7;                             // read-side row&7

    floatx4 o[MI][4];
    #pragma unroll
    for (int i = 0; i < MI; i++)
        #pragma unroll
        for (int j = 0; j < 4; j++)
            o[i][j] = (floatx4){0.f, 0.f, 0.f, 0.f};

    for (int k0 = 0; k0 < DD; k0 += 64) {
        __syncthreads();
        #pragma unroll
        for (int i = 0; i < 4; i++) {
            const int rr = w * 32 + i * 8;
            gload_lds16(A + (size_t)(row0 + rr + srow) * DD + k0 + scol,
                        &Ash[rr * 64]);
            if (TN == 128 || w < 2) {
                const int q  = rr + srow;                // B LDS row
                const int bq = (q & ~63) | tau_pos(q & 63);  // tau src row
                gload_lds16(BT + (size_t)(col0 + bq) * DD + k0 + scol,
                            &Bsh[rr * 64]);
            }
        }
        __syncthreads();
        #pragma unroll
        for (int ks = 0; ks < 2; ks++) {
            short8 af[MI], bf[4];
            const int ch = ((ks << 2) + grp) ^ lx7;
            #pragma unroll
            for (int i = 0; i < MI; i++)
                af[i] = *(const short8*)&Ash[(moff + i * 16 + li) * 64 + ch * 8];
            #pragma unroll
            for (int j = 0; j < 4; j++)
                bf[j] = *(const short8*)&Bsh[(noff + j * 16 + li) * 64 + ch * 8];
            #pragma unroll
            for (int i = 0; i < MI; i++)
                #pragma unroll
                for (int j = 0; j < 4; j++)
                    o[i][j] = MFMA16(af[i], bf[j], o[i][j]);
        }
    }

    const bool f32 = flags[0] != 0;
    const int cbase = col0 + noff + li * 4;              // 4 consecutive cols
    float4 b4 = load4(bias, cbase, f32);
    float bv[4] = {b4.x, b4.y, b4.z, b4.w};

    #pragma unroll
    for (int i = 0; i < MI; i++) {
        #pragma unroll
        for (int r = 0; r < 4; r++) {
            int grow = row0 + moff + i * 16 + grp * 4 + r;
            float v0 = o[i][0][r] + bv[0];
            float v1 = o[i][1][r] + bv[1];
            float v2 = o[i][2][r] + bv[2];
            float v3 = o[i][3][r] + bv[3];
            if (MODE == 0) {
                uint2 pk;
                pk.x = (unsigned)f2bf(v0) | ((unsigned)f2bf(v1) << 16);
                pk.y = (unsigned)f2bf(v2) | ((unsigned)f2bf(v3) << 16);
                *(uint2*)&((unsigned short*)outp)[(size_t)grow * NCOL + cbase] = pk;
            } else {
                int b = grow / RTOT, rr2 = grow % RTOT;
                size_t dst = (rr2 < PP)
                    ? ((size_t)(b * PP + rr2) * DD + cbase)
                    : ((size_t)BS * PP * DD + (size_t)(b * NN + (rr2 - PP)) * DD + cbase);
                *(float4*)&((float*)outp)[dst] = make_float4(v0, v1, v2, v3);
            }
        }
    }
}

// ---------------------------------------------------------------------------
// fattn3: 32 queries/wave, swapped QK^T, in-register P, V in LDS from
// sigma+tau-permuted VtG, VALU-accumulated l. REGION-BALANCED XCD swizzle
// (each XCD gets 1/8 of cross AND 1/8 of self; FETCH 74.7 -> 24.5 MB).
// ---------------------------------------------------------------------------
template<bool PACKED, int SPL>
__global__ __launch_bounds__(256, 4) void fattn3_kernel(
    const unsigned short* __restrict__ qkv,
    const unsigned short* __restrict__ VtG,      // used if PACKED
    const float* __restrict__ mb,                // log2-domain bias [BS*RTOT]
    unsigned short* __restrict__ attn_out,       // used if SPL==1
    unsigned short* __restrict__ part_o,         // used if SPL>1
    float* __restrict__ part_l)                  // used if SPL>1
{
    const int CB = BS * HH * (NN / 128);   // 384
    const int SB = BS * HH * (PP / 128);   // 96
    const int CC8 = CB * SPL / 8;          // cross blocks per XCD
    const int SC8 = SB * SPL / 8;          // self blocks per XCD

    const int xk = blockIdx.x & 7;         // XCD slot (round-robin dispatch)
    const int xj = blockIdx.x >> 3;        // position within this XCD's run
    int bid = (xj < CC8) ? (xk * CC8 + xj)
                         : (CB * SPL + xk * SC8 + (xj - CC8));
    bool cross; int chunk, v;
    if (bid < CB * SPL) { cross = true;  chunk = bid / CB; v = bid % CB; }
    else { int s = bid - CB * SPL; cross = false; chunk = s / SB; v = s % SB; }
    const int nqb  = cross ? (NN / 128) : (PP / 128);
    const int q0   = (v % nqb) * 128;
    const int h    = (v / nqb) % HH;
    const int b    = v / (nqb * HH);
    const int QOFF = cross ? PP : 0;
    const int NT   = cross ? (RTOT / 64) : (PP / 64);
    const int tpc  = NT / SPL;
    const int t_beg = chunk * tpc, t_end = chunk * tpc + tpc;
    const int rowbase = cross ? ((b * HH + h) * NN + q0)
                              : (CROWS + (b * HH + h) * PP + q0);

    alignas(16) __shared__ unsigned short Ks[64][72];
    alignas(16) __shared__ unsigned short Vt[64][72];

    const int tid  = threadIdx.x;
    const int w    = tid >> 6;
    const int lane = tid & 63;
    const int grp  = lane >> 4;
    const int li   = lane & 15;
    const int lr   = tid >> 2;
    const int ld0  = (tid & 3) << 4;

    // Q B-frags: 2 q-tiles of 16 per wave (queries q0 + w*32 + qi*16 + li)
    short8 qf[2][2];
    #pragma unroll
    for (int qi = 0; qi < 2; qi++) {
        const unsigned short* qp = qkv +
            (size_t)(b * RTOT + QOFF + q0 + w * 32 + qi * 16 + li) * QKVC
            + h * HD + grp * 8;
        qf[qi][0] = *(const short8*)(qp);
        qf[qi][1] = *(const short8*)(qp + 32);
    }

    floatx4 o[2][4];
    #pragma unroll
    for (int qi = 0; qi < 2; qi++)
        #pragma unroll
        for (int n = 0; n < 4; n++)
            o[qi][n] = (floatx4){0.f, 0.f, 0.f, 0.f};
    float lp[2] = {0.f, 0.f};   // per-lane l partial for query (lane&15)

    // ---- incremental K/V source pointers + first-tile register prefetch ----
    const unsigned short* kptr = qkv +
        (size_t)(b * RTOT + t_beg * 64 + lr) * QKVC + DD + h * HD + ld0;
    const unsigned short* vptr = PACKED
        ? VtG + ((size_t)(b * HH + h) * HD + lr) * RTOT + t_beg * 64 + ld0
        : kptr + DD;
    const float* mbp = mb + b * RTOT + t_beg * 64 + grp * 4;

    uint4 kr0, kr1, vr0, vr1;
    kr0 = ((const uint4*)kptr)[0];
    kr1 = ((const uint4*)kptr)[1];
    vr0 = ((const uint4*)vptr)[0];
    vr1 = ((const uint4*)vptr)[1];
    kptr += (size_t)64 * QKVC;
    vptr += PACKED ? 64 : (size_t)64 * QKVC;

    for (int t = t_beg; t < t_end; t++) {
        __syncthreads();   // all waves done reading Ks/Vt of previous tile
        // ---- stage from registers ----
        *(uint4*)&Ks[lr][ld0]     = kr0;
        *(uint4*)&Ks[lr][ld0 + 8] = kr1;
        if (PACKED) {
            *(uint4*)&Vt[lr][ld0]     = vr0;   // VtG already sigma+tau-permuted
            *(uint4*)&Vt[lr][ld0 + 8] = vr1;
        } else {
            unsigned short tmp[16];
            *(uint4*)&tmp[0] = vr0;
            *(uint4*)&tmp[8] = vr1;
            const int slr = sigma_pos(lr);     // key lr stored at column slr
            #pragma unroll
            for (int j = 0; j < 16; j++)
                Vt[tau_inv(ld0 + j)][slr] = tmp[j];   // dv d at row tau_inv(d)
        }
        __syncthreads();

        // ---- prefetch next tile (overlaps compute) ----
        if (t + 1 < t_end) {
            kr0 = ((const uint4*)kptr)[0];
            kr1 = ((const uint4*)kptr)[1];
            vr0 = ((const uint4*)vptr)[0];
            vr1 = ((const uint4*)vptr)[1];
            kptr += (size_t)64 * QKVC;
            vptr += PACKED ? 64 : (size_t)64 * QKVC;
        }

        // ---- S^T = K Q^T: lane holds P-row of query li, keys n*16+grp*4+r --
        floatx4 sfT[2][4];
        __builtin_amdgcn_s_setprio(1);
        #pragma unroll
        for (int n = 0; n < 4; n++) {
            short8 kb0 = *(const short8*)&Ks[n * 16 + li][grp * 8];
            short8 kb1 = *(const short8*)&Ks[n * 16 + li][32 + grp * 8];
            #pragma unroll
            for (int qi = 0; qi < 2; qi++) {
                floatx4 acc = {0.f, 0.f, 0.f, 0.f};
                acc = MFMA16(kb0, qf[qi][0], acc);
                acc = MFMA16(kb1, qf[qi][1], acc);
                sfT[qi][n] = acc;
            }
        }
        __builtin_amdgcn_s_setprio(0);

        floatx4 mbv[4];
        #pragma unroll
        for (int n = 0; n < 4; n++)
            mbv[n] = *(const floatx4*)(mbp + n * 16);
        mbp += 64;

        // ---- softmax in log2 domain; trunc-bf16 P packed in-register into
        //      the PV A-fragment (sigma key order) ----
        short8 pa[2][2];
        #pragma unroll
        for (int qi = 0; qi < 2; qi++) {
            unsigned u[4][4];
            #pragma unroll
            for (int n = 0; n < 4; n++) {
                #pragma unroll
                for (int r = 0; r < 4; r++) {
                    float e = __builtin_amdgcn_exp2f(
                        fmaf(sfT[qi][n][r], SCL2, mbv[n][r]));
                    u[n][r] = __float_as_uint(e);
                    lp[qi] += __uint_as_float(u[n][r] & 0xffff0000u);
                }
            }
            #pragma unroll
            for (int s2 = 0; s2 < 2; s2++) {
                uint4 pk;
                pk.x = __builtin_amdgcn_perm(u[2*s2][1],   u[2*s2][0],   0x07060302u);
                pk.y = __builtin_amdgcn_perm(u[2*s2][3],   u[2*s2][2],   0x07060302u);
                pk.z = __builtin_amdgcn_perm(u[2*s2+1][1], u[2*s2+1][0], 0x07060302u);
                pk.w = __builtin_amdgcn_perm(u[2*s2+1][3], u[2*s2+1][2], 0x07060302u);
                pa[qi][s2] = __builtin_bit_cast(short8, pk);
            }
        }

        // ---- O += P V (P in registers; O slot n2 = true dv li*4+n2) ----
        __builtin_amdgcn_s_setprio(1);
        #pragma unroll
        for (int s2 = 0; s2 < 2; s2++) {
            #pragma unroll
            for (int n2 = 0; n2 < 4; n2++) {
                short8 vf = *(const short8*)&Vt[n2 * 16 + li][s2 * 32 + grp * 8];
                o[0][n2] = MFMA16(pa[0][s2], vf, o[0][n2]);
                o[1][n2] = MFMA16(pa[1][s2], vf, o[1][n2]);
            }
        }
        __builtin_amdgcn_s_setprio(0);
    }

    // ---- l reduction: sum the 4 grp-partials for each query ----
    float lfull[2];
    #pragma unroll
    for (int qi = 0; qi < 2; qi++) {
        float l = lp[qi];
        l += __shfl_xor(l, 16);
        l += __shfl_xor(l, 32);
        lfull[qi] = l;    // value for query (lane&15), replicated across grps
    }

    // ---- epilogue: dv of o[qi][n2][r] is li*4+n2 -> packed uint2 stores ----
    if (SPL > 1) {
        #pragma unroll
        for (int qi = 0; qi < 2; qi++)
            #pragma unroll
            for (int r = 0; r < 4; r++) {
                float lv = __shfl(lfull[qi], grp * 4 + r);
                size_t row = (size_t)chunk * TROWS + rowbase
                           + w * 32 + qi * 16 + grp * 4 + r;
                uint2 pk;
                pk.x = (unsigned)f2bf(o[qi][0][r]) | ((unsigned)f2bf(o[qi][1][r]) << 16);
                pk.y = (unsigned)f2bf(o[qi][2][r]) | ((unsigned)f2bf(o[qi][3][r]) << 16);
                *(uint2*)&part_o[row * 64 + li * 4] = pk;
                if (li == 0) part_l[row] = lv;
            }
    } else {
        #pragma unroll
        for (int qi = 0; qi < 2; qi++)
            #pragma unroll
            for (int r = 0; r < 4; r++) {
                float inv = 1.0f / __shfl(lfull[qi], grp * 4 + r);
                int qloc = q0 + w * 32 + qi * 16 + grp * 4 + r;
                if (cross) {
                    size_t row = (size_t)(b * RTOT + PP + qloc);
                    uint2 pk;
                    pk.x = (unsigned)f2bf(o[qi][0][r] * inv)
                         | ((unsigned)f2bf(o[qi][1][r] * inv) << 16);
                    pk.y = (unsigned)f2bf(o[qi][2][r] * inv)
                         | ((unsigned)f2bf(o[qi][3][r] * inv) << 16);
                    *(uint2*)&attn_out[row * DD + h * HD + li * 4] = pk;
                } else {
                    #pragma unroll
                    for (int n2 = 0; n2 < 4; n2++) {
                        int dc = li * 4 + n2;
                        int f = h * (HD * PP) + dc * PP + qloc;
                        attn_out[(size_t)(b * RTOT + f / DD) * DD + (f % DD)]
                            = f2bf(o[qi][n2][r] * inv);
                    }
                }
            }
    }
}

// ---------------------------------------------------------------------------
// Split-K combine. Cross: 16 rows/block (4 independent row-chains/thread for
// ILP; grid 12288 -> 3072 blocks). Self: 64-row LDS transpose blocks.
// ---------------------------------------------------------------------------
template<int SPL>
__global__ __launch_bounds__(256) void combine_kernel(
    const unsigned short* __restrict__ part_o,
    const float* __restrict__ part_l,
    unsigned short* __restrict__ attn_out)
{
    const int CBLK = CROWS / 16;           // 3072
    if (blockIdx.x < CBLK) {
        const int rbase = blockIdx.x * 16 + (threadIdx.x >> 6) * 4;
        const int dv    = threadIdx.x & 63;
        #pragma unroll
        for (int r4 = 0; r4 < 4; r4++) {
            const int row = rbase + r4;
            float l = 0.f, ov = 0.f;
            #pragma unroll
            for (int c = 0; c < SPL; c++) {
                l  += part_l[(size_t)c * TROWS + row];
                ov += bf2f(part_o[((size_t)c * TROWS + row) * 64 + dv]);
            }
            float res = ov / l;
            int b = row / (HH * NN), rem = row % (HH * NN);
            int h = rem / NN, n = rem % NN;
            attn_out[(size_t)(b * RTOT + PP + n) * DD + h * HD + dv] = f2bf(res);
        }
        return;
    }
    // ---- self rows: 64 rows/block, transpose in LDS ----
    __shared__ unsigned short T[64][72];
    const int blk = blockIdx.x - CBLK;     // 0..SROWS/64-1
    const int r0b = blk * 64;              // offset into self region
    {
        const int rp  = threadIdx.x >> 2;          // row in group
        const int d0  = (threadIdx.x & 3) * 16;
        const int row = CROWS + r0b + rp;
        float l = 0.f;
        float ov[16] = {};
        #pragma unroll
        for (int c = 0; c < SPL; c++) {
            l += part_l[(size_t)c * TROWS + row];
            const uint4* po = (const uint4*)&part_o[((size_t)c * TROWS + row) * 64 + d0];
            uint4 x0 = po[0], x1 = po[1];
            const unsigned short* u0 = (const unsigned short*)&x0;
            const unsigned short* u1 = (const unsigned short*)&x1;
            #pragma unroll
            for (int k = 0; k < 8; k++) { ov[k] += bf2f(u0[k]); ov[8 + k] += bf2f(u1[k]); }
        }
        float inv = 1.0f / l;
        #pragma unroll
        for (int k = 0; k < 16; k++) T[rp][d0 + k] = f2bf(ov[k] * inv);
    }
    __syncthreads();
    {
        const int dv = threadIdx.x >> 2;
        const int pc = (threadIdx.x & 3) * 16;
        const int bh = r0b / PP;           // b*HH + h
        const int p0 = r0b % PP;
        const int b = bh / HH, h = bh % HH;
        unsigned short tmp[16];
        #pragma unroll
        for (int k = 0; k < 16; k++) tmp[k] = T[pc + k][dv];
        size_t base = (size_t)b * RTOT * DD + (size_t)h * (HD * PP)
                    + (size_t)dv * PP + p0 + pc;
        *(uint4*)&attn_out[base]     = *(uint4*)&tmp[0];
        *(uint4*)&attn_out[base + 8] = *(uint4*)&tmp[8];
    }
}

// ---------------------------------------------------------------------------
// Round-9 fattn (fallback tier, online softmax, reads mask directly).
// ---------------------------------------------------------------------------
template<int MODE>
__global__ __launch_bounds__(256) void fattn_kernel(
    const __hip_bfloat16* __restrict__ qkv,
    const void* __restrict__ mask,
    const int* __restrict__ flags,
    __hip_bfloat16* __restrict__ attn_out)
{
    constexpr int NQ    = (MODE == 0) ? NN : PP;
    constexpr int NK    = (MODE == 0) ? RTOT : PP;
    constexpr int QOFF  = (MODE == 0) ? PP : 0;
    constexpr int NTILE = NK / 64;

    alignas(16) __shared__ unsigned short Ks[64][72];
    alignas(16) __shared__ unsigned short Vt[64][72];
    alignas(16) __shared__ unsigned short Psm[4][16][72];

    const int tid   = threadIdx.x;
    const int w     = tid >> 6;
    const int lane  = tid & 63;
    const int grp   = lane >> 4;
    const int li    = lane & 15;
    const int nqb   = NQ / 64;
    const int q0    = (blockIdx.x % nqb) * 64;
    const int h     = (blockIdx.x / nqb) % HH;
    const int b     = blockIdx.x / (nqb * HH);
    const int mtype = flags[1];

    const unsigned short* qkv_u = (const unsigned short*)qkv;
    const int lr  = tid >> 2;
    const int ld0 = (tid & 3) << 4;

    short8 qf[2];
    {
        const unsigned short* qp = qkv_u +
            (size_t)(b * RTOT + QOFF + q0 + w * 16 + li) * QKVC + h * HD + grp * 8;
        qf[0] = *(const short8*)(qp);
        qf[1] = *(const short8*)(qp + 32);
    }

    floatx4 o[4] = {{0.f,0.f,0.f,0.f},{0.f,0.f,0.f,0.f},
                    {0.f,0.f,0.f,0.f},{0.f,0.f,0.f,0.f}};
    float mrun[4] = {-3e38f, -3e38f, -3e38f, -3e38f};
    float lrun[4] = {0.f, 0.f, 0.f, 0.f};

    for (int t = 0; t < NTILE; t++) {
        const int m0 = t * 64;
        __syncthreads();
        {
            const unsigned short* kp = qkv_u +
                (size_t)(b * RTOT + m0 + lr) * QKVC + DD + h * HD + ld0;
            *(uint4*)&Ks[lr][ld0]     = ((const uint4*)kp)[0];
            *(uint4*)&Ks[lr][ld0 + 8] = ((const uint4*)kp)[1];
            const unsigned short* vp = kp + DD;
            unsigned short tmp[16];
            *(uint4*)&tmp[0] = ((const uint4*)vp)[0];
            *(uint4*)&tmp[8] = ((const uint4*)vp)[1];
            #pragma unroll
            for (int j = 0; j < 16; j++) Vt[ld0 + j][lr] = tmp[j];
        }
        __syncthreads();

        floatx4 sf[4];
        #pragma unroll
        for (int n = 0; n < 4; n++) {
            floatx4 acc = {0.f, 0.f, 0.f, 0.f};
            short8 kb0 = *(const short8*)&Ks[n * 16 + li][grp * 8];
            short8 kb1 = *(const short8*)&Ks[n * 16 + li][32 + grp * 8];
            acc = MFMA16(qf[0], kb0, acc);
            acc = MFMA16(qf[1], kb1, acc);
            sf[n] = acc;
        }

        bool mk[4];
        #pragma unroll
        for (int n = 0; n < 4; n++) {
            int m = m0 + n * 16 + li;
            mk[n] = (m < PP) && mask_at(mask, b * PP + m, mtype);
        }

        #pragma unroll
        for (int r = 0; r < 4; r++) {
            float sv[4];
            #pragma unroll
            for (int n = 0; n < 4; n++)
                sv[n] = mk[n] ? -1e30f : sf[n][r] * 0.125f;
            float tm = fmaxf(fmaxf(sv[0], sv[1]), fmaxf(sv[2], sv[3]));
            #pragma unroll
            for (int off = 1; off < 16; off <<= 1)
                tm = fmaxf(tm, __shfl_xor(tm, off));
            float mnew = fmaxf(mrun[r], tm);
            float al = __expf(mrun[r] - mnew);
            float p[4], ts = 0.f;
            #pragma unroll
            for (int n = 0; n < 4; n++) {
                p[n] = (sv[n] < -1e29f) ? 0.f : __expf(sv[n] - mnew);
                ts += p[n];
            }
            #pragma unroll
            for (int off = 1; off < 16; off <<= 1)
                ts += __shfl_xor(ts, off);
            mrun[r] = mnew;
            lrun[r] = lrun[r] * al + ts;
            #pragma unroll
            for (int n = 0; n < 4; n++) {
                o[n][r] *= al;
                Psm[w][grp * 4 + r][n * 16 + li] = f2bf(p[n]);
            }
        }
        __syncthreads();

        #pragma unroll
        for (int s2 = 0; s2 < 2; s2++) {
            short8 pa = *(const short8*)&Psm[w][li][s2 * 32 + grp * 8];
            #pragma unroll
            for (int n2 = 0; n2 < 4; n2++) {
                short8 vf = *(const short8*)&Vt[n2 * 16 + li][s2 * 32 + grp * 8];
                o[n2] = MFMA16(pa, vf, o[n2]);
            }
        }
    }

    unsigned short* ao = (unsigned short*)attn_out;
    #pragma unroll
    for (int r = 0; r < 4; r++) {
        float inv = 1.0f / lrun[r];
        int qloc = q0 + w * 16 + grp * 4 + r;
        if (MODE == 0) {
            size_t row = (size_t)(b * RTOT + PP + qloc);
            #pragma unroll
            for (int n2 = 0; n2 < 4; n2++)
                ao[row * DD + h * HD + n2 * 16 + li] = f2bf(o[n2][r] * inv);
        } else {
            #pragma unroll
            for (int n2 = 0; n2 < 4; n2++) {
                int dc = n2 * 16 + li;
                int f = h * (HD * PP) + dc * PP + qloc;
                ao[(size_t)(b * RTOT + f / DD) * DD + (f % DD)] = f2bf(o[n2][r] * inv);
            }
        }
    }
}

// ---------------------------------------------------------------------------
// Vector GEMM fallback (last-resort tier).
// ---------------------------------------------------------------------------
template<int MODE, int NCOL, typename OutT>
__global__ __launch_bounds__(256) void gemm_kernel(
    const void* __restrict__ A0, const void* __restrict__ A1,
    const void* __restrict__ W, const void* __restrict__ bias,
    const int* __restrict__ flags, OutT* __restrict__ out)
{
    const bool f32 = flags[0] != 0;
    alignas(16) __shared__ float As[16][68];
    alignas(16) __shared__ float Bsh2[16][68];
    const int tid  = threadIdx.x;
    const int row0 = blockIdx.y * 64;
    const int col0 = blockIdx.x * 64;
    const int ty = tid >> 4, tx = tid & 15;
    const int a_row = tid >> 2;
    const int a_k4  = (tid & 3) * 4;
    const int grow  = row0 + a_row;
    const void* abase; size_t aoff; bool af32;
    if (MODE == 0) {
        int b = grow / RTOT, r = grow % RTOT;
        if (r < NN) { abase = A0; aoff = (size_t)(b * NN + r) * DD; }
        else        { abase = A1; aoff = (size_t)(b * PP + (r - NN)) * DD; }
        af32 = f32;
    } else {
        abase = A0; aoff = (size_t)grow * DD; af32 = false;
    }
    const int b_k  = tid >> 4;
    const int b_n4 = (tid & 15) * 4;
    float acc[4][4] = {};
    for (int k0 = 0; k0 < DD; k0 += 16) {
        float4 fa = load4(abase, aoff + k0 + a_k4, af32);
        As[a_k4 + 0][a_row] = fa.x;
        As[a_k4 + 1][a_row] = fa.y;
        As[a_k4 + 2][a_row] = fa.z;
        As[a_k4 + 3][a_row] = fa.w;
        float4 fb = load4(W, (size_t)(k0 + b_k) * NCOL + col0 + b_n4, f32);
        *(float4*)&Bsh2[b_k][b_n4] = fb;
        __syncthreads();
        #pragma unroll
        for (int kk = 0; kk < 16; kk++) {
            float4 av = *(const float4*)&As[kk][ty * 4];
            float4 bvv = *(const float4*)&Bsh2[kk][tx * 4];
            float a_[4] = {av.x, av.y, av.z, av.w};
            float b_[4] = {bvv.x, bvv.y, bvv.z, bvv.w};
            #pragma unroll
            for (int i = 0; i < 4; i++)
                #pragma unroll
                for (int j = 0; j < 4; j++)
                    acc[i][j] += a_[i] * b_[j];
        }
        __syncthreads();
    }
    #pragma unroll
    for (int i = 0; i < 4; i++) {
        int gr = row0 + ty * 4 + i;
        #pragma unroll
        for (int j = 0; j < 4; j++) {
            int gc = col0 + tx * 4 + j;
            float v = acc[i][j] + load1(bias, gc, f32);
            if (MODE == 0) {
                store_out(out, (size_t)gr * NCOL + gc, v);
            } else {
                int b = gr / RTOT, r = gr % RTOT;
                size_t dst = (r < PP)
                    ? ((size_t)(b * PP + r) * DD + gc)
                    : ((size_t)BS * PP * DD + (size_t)(b * NN + (r - PP)) * DD + gc);
                store_out(out, dst, v);
            }
        }
    }
}

// ---------------------------------------------------------------------------
extern "C" void kernel_launch(void* const* d_in, const int* in_sizes, int n_in,
                              void* d_out, int out_size, void* d_ws, size_t ws_size,
                              hipStream_t stream) {
    const void *xs = nullptr, *xq = nullptr, *mask = nullptr,
               *qkv_w = nullptr, *qkv_b = nullptr, *proj_w = nullptr, *proj_b = nullptr;
    for (int i = 0; i < n_in; i++) {
        switch (in_sizes[i]) {
            case BS * PP * DD:   xs     = d_in[i]; break;
            case BS * NN * DD:   xq     = d_in[i]; break;
            case BS * PP:        mask   = d_in[i]; break;
            case DD * QKVC:      qkv_w  = d_in[i]; break;
            case QKVC:           qkv_b  = d_in[i]; break;
            case DD * DD:        proj_w = d_in[i]; break;
            case DD:             proj_b = d_in[i]; break;
        }
    }
    if (!xs || !xq || !mask || !qkv_w || !qkv_b || !proj_w || !proj_b) {
        xs = d_in[0]; xq = d_in[1]; mask = d_in[2];
        qkv_w = d_in[3]; qkv_b = d_in[4]; proj_w = d_in[5]; proj_b = d_in[6];
    }
    float* out = (float*)d_out;

    const size_t off_mb   = 256;
    const size_t off_full = off_mb   + (size_t)BS * RTOT * 4;
    const size_t off_ab   = off_full + (size_t)MTOT * QKVC * 2;
    const size_t off_w    = off_ab   + (size_t)MTOT * DD * 2;
    const size_t off_wp   = off_w    + (size_t)QKVC * DD * 2;
    const size_t off_vt   = off_wp   + (size_t)DD * DD * 2;
    const size_t off_po   = off_vt   + (size_t)BS * HH * HD * RTOT * 2;
    // SPL=4 tier
    const size_t off_ml4  = off_po   + (size_t)4 * TROWS * 64 * 2;
    const size_t need_A4  = off_ml4  + (size_t)4 * TROWS * 4;
    // SPL=2 tier
    const size_t off_ml2  = off_po   + (size_t)2 * TROWS * 64 * 2;
    const size_t need_A2  = off_ml2  + (size_t)2 * TROWS * 4;
    const size_t need_B   = off_po;
    const size_t need_C   = off_vt;

    const size_t r_full = 256;
    const size_t r_ab   = r_full + (size_t)MTOT * QKVC * 2;
    const size_t r_wq   = r_ab   + (size_t)MTOT * DD * 2;
    const size_t r_wp   = r_wq   + (size_t)QKVC * DD * 2;
    const size_t need_R = r_wp   + (size_t)DD * DD * 2;

    int* flags = (int*)d_ws;
    const int NCMB = CROWS / 16 + SROWS / 64;   // combine grid (3264)
    const int NPRP = 1 + CBL + TQKV + TPRJ;     // prep grid (1857)

    if (ws_size >= need_C) {
        float* mb               = (float*)((char*)d_ws + off_mb);
        unsigned short* fullqkv = (unsigned short*)((char*)d_ws + off_full);
        unsigned short* attn    = (unsigned short*)((char*)d_ws + off_ab);
        unsigned short* WqkvT   = (unsigned short*)((char*)d_ws + off_w);
        unsigned short* WprojT  = (unsigned short*)((char*)d_ws + off_wp);
        unsigned short* VtG     = (unsigned short*)((char*)d_ws + off_vt);
        unsigned short* part_o  = (unsigned short*)((char*)d_ws + off_po);

        prep_kernel<<<NPRP, 256, 0, stream>>>(
            xq, xs, qkv_w, proj_w, mask, flags, mb,
            attn /*as Abf*/, WqkvT, WprojT);

        mgemm_kernel<0, QKVC, 128><<<dim3(QKVC / 128, MTOT / 128), 256, 0, stream>>>(
            attn /*Abf*/, WqkvT, qkv_b, flags, (void*)fullqkv);

        const int CB = BS * HH * (NN / 128), SB = BS * HH * (PP / 128);
        if (ws_size >= need_A4) {
            float* part_l = (float*)((char*)d_ws + off_ml4);
            vtprep_kernel<<<dim3(RTOT / 64, BS * HH), 256, 0, stream>>>(fullqkv, VtG);
            fattn3_kernel<true, 4><<<(CB + SB) * 4, 256, 0, stream>>>(
                fullqkv, VtG, mb, nullptr, part_o, part_l);
            combine_kernel<4><<<NCMB, 256, 0, stream>>>(part_o, part_l, attn);
        } else if (ws_size >= need_A2) {
            float* part_l = (float*)((char*)d_ws + off_ml2);
            vtprep_kernel<<<dim3(RTOT / 64, BS * HH), 256, 0, stream>>>(fullqkv, VtG);
            fattn3_kernel<true, 2><<<(CB + SB) * 2, 256, 0, stream>>>(
                fullqkv, VtG, mb, nullptr, part_o, part_l);
            combine_kernel<2><<<NCMB, 256, 0, stream>>>(part_o, part_l, attn);
        } else if (ws_size >= need_B) {
            vtprep_kernel<<<dim3(RTOT / 64, BS * HH), 256, 0, stream>>>(fullqkv, VtG);
            fattn3_kernel<true, 1><<<CB + SB, 256, 0, stream>>>(
                fullqkv, VtG, mb, attn, nullptr, nullptr);
        } else {
            fattn3_kernel<false, 1><<<CB + SB, 256, 0, stream>>>(
                fullqkv, nullptr, mb, attn, nullptr, nullptr);
        }

        mgemm_kernel<1, DD, 64><<<dim3(DD / 64, MTOT / 128), 256, 0, stream>>>(
            attn, WprojT, proj_b, flags, (void*)out);
    } else if (ws_size >= need_R) {
        unsigned short* fullqkv = (unsigned short*)((char*)d_ws + r_full);
        unsigned short* attn    = (unsigned short*)((char*)d_ws + r_ab);
        unsigned short* WqkvT   = (unsigned short*)((char*)d_ws + r_wq);
        unsigned short* WprojT  = (unsigned short*)((char*)d_ws + r_wp);

        prep_kernel<<<NPRP, 256, 0, stream>>>(
            xq, xs, qkv_w, proj_w, mask, flags, nullptr,
            attn, WqkvT, WprojT);
        mgemm_kernel<0, QKVC, 128><<<dim3(QKVC / 128, MTOT / 128), 256, 0, stream>>>(
            attn, WqkvT, qkv_b, flags, (void*)fullqkv);
        fattn_kernel<0><<<BS * HH * (NN / 64), 256, 0, stream>>>(
            (const __hip_bfloat16*)fullqkv, mask, flags, (__hip_bfloat16*)attn);
        fattn_kernel<1><<<BS * HH * (PP / 64), 256, 0, stream>>>(
            (const __hip_bfloat16*)fullqkv, mask, flags, (__hip_bfloat16*)attn);
        mgemm_kernel<1, DD, 64><<<dim3(DD / 64, MTOT / 128), 256, 0, stream>>>(
            attn, WprojT, proj_b, flags, (void*)out);
    } else {
        __hip_bfloat16* fullqkv = (__hip_bfloat16*)((char*)d_ws + 256);
        __hip_bfloat16* attn    = fullqkv + (size_t)MTOT * QKVC;
        detect_kernel<<<1, 256, 0, stream>>>(qkv_w, mask, flags, nullptr, 0);
        gemm_kernel<0, QKVC, __hip_bfloat16>
            <<<dim3(QKVC / 64, MTOT / 64), 256, 0, stream>>>(
            xq, xs, qkv_w, qkv_b, flags, fullqkv);
        fattn_kernel<0><<<BS * HH * (NN / 64), 256, 0, stream>>>(fullqkv, mask, flags, attn);
        fattn_kernel<1><<<BS * HH * (PP / 64), 256, 0, stream>>>(fullqkv, mask, flags, attn);
        gemm_kernel<1, DD, float>
            <<<dim3(DD / 64, MTOT / 64), 256, 0, stream>>>(
            attn, nullptr, proj_w, proj_b, flags, out);
    }
}